// Round 1
// baseline (558.366 us; speedup 1.0000x reference)
//
#include <hip/hip_runtime.h>
#include <math.h>

// GSA linear attention, fp32 correctness-first version.
//
// Algebra: out[b] = WM[b] @ img[b] + b_out, with
//   ctx[b,h,d,e] = softmax_n(k[b,h,d,:]) . v[b,h,e,:]
//   M[b,o,hd]    = sum_e w_out[o, h*64+e] * ctx[b,h,d,e]
//   WM[b,o,c]    = sum_hd M[b,o,hd] * Wq[hd,c]
// k rows of w_qkv: [512..1023], v rows: [1024..1535], q rows: [0..511].
// Softmax computed without max-subtraction (logits ~N(0,1), exp range safe in fp32).

#define BATCH 8
#define CIN 256
#define NSP 4096
#define HEADS 8
#define DK 64
#define HID 512
#define OC 256
#define NCHUNK 8

// ---------------- K1: per (b,h,chunk) compute unnormalized ctx partials ----------------
// Block = 256 threads. Per block: 512 n-positions as 8 tiles of 64.
// Phase 1: tiled GEMM kv[128 rows][64 n] = W_{k,v}[128][256] @ img[256][64n]
// Phase 2: ctx[d][e] += exp(k[d][n]) * v[e][n];  Z[d] += exp(k[d][n])
__global__ __launch_bounds__(256) void k1_ctx_partial(
    const float* __restrict__ img, const float* __restrict__ w_qkv,
    float* __restrict__ ctx_part, float* __restrict__ z_part)
{
  const int chunk = blockIdx.x;
  const int h = blockIdx.y;
  const int b = blockIdx.z;
  const int tid = threadIdx.x;

  __shared__ float xt[64][68];     // [c-tile][n-tile], padded for float4 align
  __shared__ float ubuf[8448];     // union: wt[128][65]  |  kvT[64][132]

  const float* imgb = img + (size_t)b * CIN * NSP;
  const float* Wk = w_qkv + (size_t)(HID + h * DK) * CIN;
  const float* Wv = w_qkv + (size_t)(2 * HID + h * DK) * CIN;

  const int cg = tid & 15;   // phase-1: n cols cg*4..+3
  const int rg = tid >> 4;   // phase-1: rows rg*8..+7
  const int d  = tid >> 2;   // phase-2: k row
  const int eb = tid & 3;    // phase-2: e block (16 wide)

  float cacc[16];
#pragma unroll
  for (int j = 0; j < 16; ++j) cacc[j] = 0.f;
  float zacc = 0.f;

  for (int t = 0; t < 8; ++t) {
    const int n0 = chunk * 512 + t * 64;
    float acc[8][4];
#pragma unroll
    for (int i = 0; i < 8; ++i)
#pragma unroll
      for (int j = 0; j < 4; ++j) acc[i][j] = 0.f;

    for (int ct = 0; ct < 4; ++ct) {
      // stage img tile [64c][64n]
      for (int i = tid; i < 64 * 64; i += 256) {
        int cc = i >> 6, nn = i & 63;
        xt[cc][nn] = imgb[(size_t)(ct * 64 + cc) * NSP + n0 + nn];
      }
      // stage W tile [128 rows][64 c] (rows 0..63 = Wk, 64..127 = Wv)
      for (int i = tid; i < 128 * 64; i += 256) {
        int r = i >> 6, cc = i & 63;
        const float* Wr = (r < 64) ? (Wk + (size_t)r * CIN) : (Wv + (size_t)(r - 64) * CIN);
        ubuf[r * 65 + cc] = Wr[ct * 64 + cc];
      }
      __syncthreads();
      for (int cc = 0; cc < 64; ++cc) {
        float4 xv = *(const float4*)&xt[cc][cg * 4];
#pragma unroll
        for (int i = 0; i < 8; ++i) {
          float w = ubuf[(rg * 8 + i) * 65 + cc];
          acc[i][0] += w * xv.x;
          acc[i][1] += w * xv.y;
          acc[i][2] += w * xv.z;
          acc[i][3] += w * xv.w;
        }
      }
      __syncthreads();
    }
    // write kv tile transposed into ubuf as kvT[n][row]
#pragma unroll
    for (int j = 0; j < 4; ++j)
#pragma unroll
      for (int i = 0; i < 8; ++i)
        ubuf[(cg * 4 + j) * 132 + rg * 8 + i] = acc[i][j];
    __syncthreads();

    // phase 2: outer-product accumulation
    for (int nn = 0; nn < 64; ++nn) {
      float ed = expf(ubuf[nn * 132 + d]);
      if (eb == 0) zacc += ed;
      const float4* vp = (const float4*)&ubuf[nn * 132 + 64 + eb * 16];
      float4 v0 = vp[0], v1 = vp[1], v2 = vp[2], v3 = vp[3];
      cacc[0]  += ed * v0.x; cacc[1]  += ed * v0.y; cacc[2]  += ed * v0.z; cacc[3]  += ed * v0.w;
      cacc[4]  += ed * v1.x; cacc[5]  += ed * v1.y; cacc[6]  += ed * v1.z; cacc[7]  += ed * v1.w;
      cacc[8]  += ed * v2.x; cacc[9]  += ed * v2.y; cacc[10] += ed * v2.z; cacc[11] += ed * v2.w;
      cacc[12] += ed * v3.x; cacc[13] += ed * v3.y; cacc[14] += ed * v3.z; cacc[15] += ed * v3.w;
    }
    __syncthreads();
  }

  float* cp = ctx_part + ((((size_t)b * HEADS + h) * NCHUNK + chunk) * DK + d) * DK + eb * 16;
  *(float4*)&cp[0]  = make_float4(cacc[0],  cacc[1],  cacc[2],  cacc[3]);
  *(float4*)&cp[4]  = make_float4(cacc[4],  cacc[5],  cacc[6],  cacc[7]);
  *(float4*)&cp[8]  = make_float4(cacc[8],  cacc[9],  cacc[10], cacc[11]);
  *(float4*)&cp[12] = make_float4(cacc[12], cacc[13], cacc[14], cacc[15]);
  if (eb == 0)
    z_part[(((size_t)b * HEADS + h) * NCHUNK + chunk) * DK + d] = zacc;
}

// ---------------- K2: reduce chunk partials + normalize by Z ----------------
__global__ __launch_bounds__(256) void k2_reduce(
    const float* __restrict__ ctx_part, const float* __restrict__ z_part,
    float* __restrict__ ctxn)
{
  const int bh = blockIdx.x;  // 0..63
  const int d = threadIdx.x >> 2, eb = threadIdx.x & 3;
  float s[16];
#pragma unroll
  for (int j = 0; j < 16; ++j) s[j] = 0.f;
  float z = 0.f;
  for (int ch = 0; ch < NCHUNK; ++ch) {
    const float* p = ctx_part + (((size_t)bh * NCHUNK + ch) * DK + d) * DK + eb * 16;
#pragma unroll
    for (int q = 0; q < 4; ++q) {
      float4 v = *(const float4*)&p[q * 4];
      s[q * 4 + 0] += v.x; s[q * 4 + 1] += v.y; s[q * 4 + 2] += v.z; s[q * 4 + 3] += v.w;
    }
    z += z_part[((size_t)bh * NCHUNK + ch) * DK + d];
  }
  const float inv = 1.f / z;
  float* dst = ctxn + ((size_t)bh * DK + d) * DK + eb * 16;
#pragma unroll
  for (int q = 0; q < 4; ++q) {
    *(float4*)&dst[q * 4] = make_float4(s[q * 4 + 0] * inv, s[q * 4 + 1] * inv,
                                        s[q * 4 + 2] * inv, s[q * 4 + 3] * inv);
  }
}

// ---------------- K3a: M[b,o,h*64+d] = sum_e w_out[o,h*64+e] * ctx[b,h,d,e] ----------------
__global__ __launch_bounds__(256) void k3a_fold_out(
    const float* __restrict__ ctxn, const float* __restrict__ w_out,
    float* __restrict__ M)
{
  const int h = blockIdx.x, b = blockIdx.y;
  const int o = threadIdx.x;
  __shared__ float cs[64][64];
  for (int i = threadIdx.x; i < 4096; i += 256) {
    cs[i >> 6][i & 63] = ctxn[(((size_t)b * HEADS + h) * DK + (i >> 6)) * DK + (i & 63)];
  }
  __syncthreads();
  float4 wreg[16];
#pragma unroll
  for (int q = 0; q < 16; ++q)
    wreg[q] = *(const float4*)&w_out[(size_t)o * HID + h * DK + q * 4];
  for (int dd = 0; dd < 64; ++dd) {
    float a = 0.f;
#pragma unroll
    for (int q = 0; q < 16; ++q) {
      float4 w4 = wreg[q];
      a += w4.x * cs[dd][q * 4 + 0] + w4.y * cs[dd][q * 4 + 1]
         + w4.z * cs[dd][q * 4 + 2] + w4.w * cs[dd][q * 4 + 3];
    }
    M[((size_t)b * OC + o) * HID + h * DK + dd] = a;
  }
}

// ---------------- K3b: WM[b,o,c] = sum_hd M[b,o,hd] * Wq[hd,c] ----------------
__global__ __launch_bounds__(256) void k3b_fold_q(
    const float* __restrict__ M, const float* __restrict__ w_qkv,
    float* __restrict__ WM)
{
  const int ob = blockIdx.x;   // 8 o-blocks of 32
  const int cb = blockIdx.y;   // 8 c-blocks of 32
  const int b = blockIdx.z;
  const int o = ob * 32 + (threadIdx.x >> 3);
  const int c0 = cb * 32 + (threadIdx.x & 7) * 4;
  const float* Mrow = M + ((size_t)b * OC + o) * HID;
  float ax = 0.f, ay = 0.f, az = 0.f, aw = 0.f;
  for (int hd = 0; hd < HID; ++hd) {
    float m = Mrow[hd];
    float4 w4 = *(const float4*)&w_qkv[(size_t)hd * CIN + c0];
    ax += m * w4.x; ay += m * w4.y; az += m * w4.z; aw += m * w4.w;
  }
  *(float4*)&WM[((size_t)b * OC + o) * CIN + c0] = make_float4(ax, ay, az, aw);
}

// ---------------- K4: out[b,o,n] = sum_c WM[b,o,c]*img[b,c,n] + b_out[o] ----------------
__global__ __launch_bounds__(256) void k4_out(
    const float* __restrict__ WM, const float* __restrict__ img,
    const float* __restrict__ b_out, float* __restrict__ out)
{
  const int nt = blockIdx.x;   // 32 n-tiles of 128
  const int ot = blockIdx.y;   // 4 o-tiles of 64
  const int b = blockIdx.z;
  const int tid = threadIdx.x;
  const int n0 = nt * 128, o0 = ot * 64;

  __shared__ float xt[64][132];   // [c][n] padded
  __shared__ float wmt[64][65];   // [o][c] padded

  const float* imgb = img + (size_t)b * CIN * NSP;
  const float* wmb = WM + (size_t)b * OC * CIN;

  const int cg = tid & 15;  // n = cg*4..+3 and 64+cg*4..+3
  const int rg = tid >> 4;  // o rows rg*4..+3

  float acc[4][8];
#pragma unroll
  for (int i = 0; i < 4; ++i)
#pragma unroll
    for (int j = 0; j < 8; ++j) acc[i][j] = 0.f;

  for (int ct = 0; ct < 4; ++ct) {
    for (int i = tid; i < 64 * 128; i += 256) {
      int cc = i >> 7, nn = i & 127;
      xt[cc][nn] = imgb[(size_t)(ct * 64 + cc) * NSP + n0 + nn];
    }
    for (int i = tid; i < 64 * 64; i += 256) {
      int r = i >> 6, cc = i & 63;
      wmt[r][cc] = wmb[(size_t)(o0 + r) * CIN + ct * 64 + cc];
    }
    __syncthreads();
    for (int cc = 0; cc < 64; ++cc) {
      float4 x0 = *(const float4*)&xt[cc][cg * 4];
      float4 x1 = *(const float4*)&xt[cc][64 + cg * 4];
#pragma unroll
      for (int i = 0; i < 4; ++i) {
        float w = wmt[rg * 4 + i][cc];
        acc[i][0] += w * x0.x; acc[i][1] += w * x0.y;
        acc[i][2] += w * x0.z; acc[i][3] += w * x0.w;
        acc[i][4] += w * x1.x; acc[i][5] += w * x1.y;
        acc[i][6] += w * x1.z; acc[i][7] += w * x1.w;
      }
    }
    __syncthreads();
  }
#pragma unroll
  for (int i = 0; i < 4; ++i) {
    const int o = o0 + rg * 4 + i;
    const float bo = b_out[o];
    float* dst = out + ((size_t)b * OC + o) * NSP + n0;
    *(float4*)&dst[cg * 4] =
        make_float4(acc[i][0] + bo, acc[i][1] + bo, acc[i][2] + bo, acc[i][3] + bo);
    *(float4*)&dst[64 + cg * 4] =
        make_float4(acc[i][4] + bo, acc[i][5] + bo, acc[i][6] + bo, acc[i][7] + bo);
  }
}

extern "C" void kernel_launch(void* const* d_in, const int* in_sizes, int n_in,
                              void* d_out, int out_size, void* d_ws, size_t ws_size,
                              hipStream_t stream) {
  (void)in_sizes; (void)n_in; (void)out_size; (void)ws_size;
  const float* img   = (const float*)d_in[0];
  const float* w_qkv = (const float*)d_in[1];
  const float* w_out = (const float*)d_in[2];
  const float* b_out = (const float*)d_in[3];
  float* out = (float*)d_out;

  float* ws = (float*)d_ws;
  float* ctx_part = ws;                         // 8*8*8*64*64   = 2,097,152
  float* z_part   = ctx_part + 2097152;         // 8*8*8*64      = 32,768
  float* ctxn     = z_part + 32768;             // 8*8*64*64     = 262,144
  float* Mbuf     = ctxn + 262144;              // 8*256*512     = 1,048,576
  float* WMbuf    = Mbuf + 1048576;             // 8*256*256     = 524,288
  // total ~15.9 MB of d_ws

  k1_ctx_partial<<<dim3(NCHUNK, HEADS, BATCH), 256, 0, stream>>>(img, w_qkv, ctx_part, z_part);
  k2_reduce<<<dim3(64), 256, 0, stream>>>(ctx_part, z_part, ctxn);
  k3a_fold_out<<<dim3(HEADS, BATCH), 256, 0, stream>>>(ctxn, w_out, Mbuf);
  k3b_fold_q<<<dim3(8, 8, BATCH), 256, 0, stream>>>(Mbuf, w_qkv, WMbuf);
  k4_out<<<dim3(32, 4, BATCH), 256, 0, stream>>>(WMbuf, img, b_out, out);
}

// Round 2
// 191.964 us; speedup vs baseline: 2.9087x; 2.9087x over previous
//
#include <hip/hip_runtime.h>
#include <math.h>
#include <stdint.h>

// GSA linear attention — bf16 MFMA version.
// out[b] = WM[b] @ img[b] + b_out, where WM folds w_out, ctx (softmax_n(k)@v^T), Wq.
// Heavy GEMMs (kv projection, ctx outer product, final out GEMM) on matrix cores.

typedef __attribute__((ext_vector_type(8))) short bf16x8;
typedef __attribute__((ext_vector_type(4))) float f32x4;

#define BATCH 8
#define CIN 256
#define NSP 4096
#define HEADS 8
#define DK 64
#define HID 512
#define OC 256
#define NCH 8   // K1 n-chunks; chunk = 512 n = 4 tiles of 128

__device__ __forceinline__ short f2bf(float f) {
  union { float f; uint32_t u; } x; x.f = f;
  uint32_t r = x.u + 0x7fffu + ((x.u >> 16) & 1u);
  return (short)(r >> 16);
}

// ---------------- P: img [b][c][n] f32 -> imgT [b][n][c] bf16 ----------------
__global__ __launch_bounds__(256) void p_transpose(
    const float* __restrict__ img, short* __restrict__ imgT)
{
  const int ntile = blockIdx.x;  // 64 tiles of 64 n
  const int ctile = blockIdx.y;  // 4 tiles of 64 c
  const int b = blockIdx.z;
  __shared__ float t[64][65];
  const float* src = img + ((size_t)b * CIN + ctile * 64) * NSP + ntile * 64;
  for (int i = threadIdx.x; i < 4096; i += 256)
    t[i >> 6][i & 63] = src[(size_t)(i >> 6) * NSP + (i & 63)];
  __syncthreads();
  short* dst = imgT + ((size_t)b * NSP + ntile * 64) * CIN + ctile * 64;
  for (int i = threadIdx.x; i < 4096; i += 256) {
    int n = i >> 6, c = i & 63;
    dst[(size_t)n * CIN + c] = f2bf(t[c][n]);
  }
}

// ---------------- Pw: w_qkv k,v rows [512..1536) f32 -> bf16 ----------------
__global__ __launch_bounds__(256) void p_weights(
    const float* __restrict__ w_qkv, short* __restrict__ wkv)
{
  int i = blockIdx.x * 256 + threadIdx.x;  // 65536 threads x 4 elems
  const float* src = w_qkv + (size_t)HID * CIN;  // skip q rows
  float4 v = ((const float4*)src)[i];
  short r[4] = {f2bf(v.x), f2bf(v.y), f2bf(v.z), f2bf(v.w)};
  *(uint2*)(wkv + (size_t)i * 4) = *(uint2*)r;
}

// ---------------- K1: MFMA kv projection + exp + ctx outer product ----------------
// grid (NCH, HEADS, BATCH), 256 thr = 4 waves.
// Per n-tile(128): phase1 kv[128rows][128n] = Wkv[128][256] @ imgT^T (MFMA),
// phase2: ek/v -> LDS bf16, ctx[64d][64e] += ek @ v^T (MFMA over n).
__global__ __launch_bounds__(256) void k1_mfma(
    const short* __restrict__ imgT, const short* __restrict__ wkv,
    float* __restrict__ ctx_part, float* __restrict__ z_part)
{
  const int chunk = blockIdx.x, h = blockIdx.y, b = blockIdx.z;
  const int tid = threadIdx.x, w = tid >> 6, l = tid & 63;
  const int l15 = l & 15, l4 = l >> 4;

  __shared__ __align__(16) char sm[32768];
  char* wb  = sm;           // phase1 A: [128 r][64 c] bf16, XOR-swizzled
  char* xb  = sm + 16384;   // phase1 B: [128 n][64 c]
  char* ekb = sm;           // phase2 A: [64 d][128 n]
  char* vb  = sm + 16384;   // phase2 B: [64 e][128 n]

  f32x4 acc2[4];
#pragma unroll
  for (int i = 0; i < 4; ++i) acc2[i] = (f32x4){0.f, 0.f, 0.f, 0.f};
  float zacc[2][4];
#pragma unroll
  for (int i = 0; i < 2; ++i)
#pragma unroll
    for (int j = 0; j < 4; ++j) zacc[i][j] = 0.f;

  const int sr = tid >> 3;   // staging row 0..31
  const int c8 = tid & 7;    // staging 16B col
  const size_t imgT_base = (size_t)b * NSP * CIN;

  for (int t = 0; t < 4; ++t) {
    const int n0 = chunk * 512 + t * 128;
    f32x4 acc1[2][8];
#pragma unroll
    for (int i = 0; i < 2; ++i)
#pragma unroll
      for (int j = 0; j < 8; ++j) acc1[i][j] = (f32x4){0.f, 0.f, 0.f, 0.f};

    for (int ct = 0; ct < 4; ++ct) {
#pragma unroll
      for (int it = 0; it < 4; ++it) {
        int r = sr + it * 32;
        int gr = (r < 64) ? (h * 64 + r) : (HID + h * 64 + (r - 64));
        uint4 wv = *(const uint4*)(wkv + (size_t)gr * CIN + ct * 64 + c8 * 8);
        *(uint4*)(wb + r * 128 + ((c8 * 16) ^ ((r & 7) << 4))) = wv;
        uint4 xv = *(const uint4*)(imgT + imgT_base + (size_t)(n0 + r) * CIN + ct * 64 + c8 * 8);
        *(uint4*)(xb + r * 128 + ((c8 * 16) ^ ((r & 7) << 4))) = xv;
      }
      __syncthreads();
#pragma unroll
      for (int kk = 0; kk < 2; ++kk) {
        int r0 = w * 32 + l15;
        bf16x8 a0 = *(bf16x8*)(wb + r0 * 128 + ((kk * 64 + l4 * 16) ^ ((r0 & 7) << 4)));
        int r1 = r0 + 16;
        bf16x8 a1 = *(bf16x8*)(wb + r1 * 128 + ((kk * 64 + l4 * 16) ^ ((r1 & 7) << 4)));
#pragma unroll
        for (int tn = 0; tn < 8; ++tn) {
          int n = tn * 16 + l15;
          bf16x8 bv = *(bf16x8*)(xb + n * 128 + ((kk * 64 + l4 * 16) ^ ((n & 7) << 4)));
          acc1[0][tn] = __builtin_amdgcn_mfma_f32_16x16x32_bf16(a0, bv, acc1[0][tn], 0, 0, 0);
          acc1[1][tn] = __builtin_amdgcn_mfma_f32_16x16x32_bf16(a1, bv, acc1[1][tn], 0, 0, 0);
        }
      }
      __syncthreads();
    }
    // phase2 prep: waves 0,1 -> exp(k) rows 0..63; waves 2,3 -> v rows 0..63
    {
      char* dst = (w < 2) ? ekb : vb;
      const int rowbase = (w & 1) * 32;
#pragma unroll
      for (int tr = 0; tr < 2; ++tr) {
#pragma unroll
        for (int tn = 0; tn < 8; ++tn) {
          f32x4 v = acc1[tr][tn];
          int n = tn * 16 + l15;
#pragma unroll
          for (int rg = 0; rg < 4; ++rg) {
            int row = rowbase + tr * 16 + l4 * 4 + rg;
            float f = v[rg];
            if (w < 2) { f = __expf(f); zacc[tr][rg] += f; }
            *(short*)(dst + row * 256 + ((2 * n) ^ ((row & 7) << 4))) = f2bf(f);
          }
        }
      }
    }
    __syncthreads();
    // phase2 MFMA: wave w owns d-tile w (16 d) x 4 e-tiles; K = 128 n
#pragma unroll
    for (int kk = 0; kk < 4; ++kk) {
      int d = w * 16 + l15;
      bf16x8 a = *(bf16x8*)(ekb + d * 256 + ((kk * 64 + l4 * 16) ^ ((d & 7) << 4)));
#pragma unroll
      for (int te = 0; te < 4; ++te) {
        int e = te * 16 + l15;
        bf16x8 bv = *(bf16x8*)(vb + e * 256 + ((kk * 64 + l4 * 16) ^ ((e & 7) << 4)));
        acc2[te] = __builtin_amdgcn_mfma_f32_16x16x32_bf16(a, bv, acc2[te], 0, 0, 0);
      }
    }
    __syncthreads();
  }
  // write ctx partial [bh][chunk][64 d][64 e] + z [bh][chunk][64 d]
  float* cp = ctx_part + (((size_t)b * HEADS + h) * NCH + chunk) * (DK * DK);
#pragma unroll
  for (int te = 0; te < 4; ++te) {
#pragma unroll
    for (int rg = 0; rg < 4; ++rg) {
      int d = w * 16 + l4 * 4 + rg;
      int e = te * 16 + l15;
      cp[d * 64 + e] = acc2[te][rg];
    }
  }
  if (w < 2) {
#pragma unroll
    for (int tr = 0; tr < 2; ++tr) {
#pragma unroll
      for (int rg = 0; rg < 4; ++rg) {
        float z = zacc[tr][rg];
#pragma unroll
        for (int m = 1; m < 16; m <<= 1) z += __shfl_xor(z, m, 64);
        if (l15 == 0) {
          int d = (w & 1) * 32 + tr * 16 + l4 * 4 + rg;
          z_part[(((size_t)b * HEADS + h) * NCH + chunk) * DK + d] = z;
        }
      }
    }
  }
}

// ---------------- K2: reduce chunk partials + normalize by Z ----------------
__global__ __launch_bounds__(256) void k2_reduce(
    const float* __restrict__ ctx_part, const float* __restrict__ z_part,
    float* __restrict__ ctxn)
{
  const int bh = blockIdx.x;
  const int d = threadIdx.x >> 2, eb = threadIdx.x & 3;
  float s[16];
#pragma unroll
  for (int j = 0; j < 16; ++j) s[j] = 0.f;
  float z = 0.f;
  for (int ch = 0; ch < NCH; ++ch) {
    const float* p = ctx_part + (((size_t)bh * NCH + ch) * DK + d) * DK + eb * 16;
#pragma unroll
    for (int q = 0; q < 4; ++q) {
      float4 v = *(const float4*)&p[q * 4];
      s[q * 4 + 0] += v.x; s[q * 4 + 1] += v.y; s[q * 4 + 2] += v.z; s[q * 4 + 3] += v.w;
    }
    z += z_part[((size_t)bh * NCH + ch) * DK + d];
  }
  const float inv = 1.f / z;
  float* dst = ctxn + ((size_t)bh * DK + d) * DK + eb * 16;
#pragma unroll
  for (int q = 0; q < 4; ++q)
    *(float4*)&dst[q * 4] = make_float4(s[q * 4 + 0] * inv, s[q * 4 + 1] * inv,
                                        s[q * 4 + 2] * inv, s[q * 4 + 3] * inv);
}

// ---------------- K3a: M[b,o,h*64+d] = sum_e w_out[o,h*64+e] * ctx[b,h,d,e] ----------------
__global__ __launch_bounds__(256) void k3a_fold_out(
    const float* __restrict__ ctxn, const float* __restrict__ w_out,
    float* __restrict__ M)
{
  const int h = blockIdx.x, b = blockIdx.y;
  const int o = threadIdx.x;
  __shared__ float cs[64][64];
  for (int i = threadIdx.x; i < 4096; i += 256)
    cs[i >> 6][i & 63] = ctxn[(((size_t)b * HEADS + h) * DK + (i >> 6)) * DK + (i & 63)];
  __syncthreads();
  float4 wreg[16];
#pragma unroll
  for (int q = 0; q < 16; ++q)
    wreg[q] = *(const float4*)&w_out[(size_t)o * HID + h * DK + q * 4];
  for (int dd = 0; dd < 64; ++dd) {
    float a = 0.f;
#pragma unroll
    for (int q = 0; q < 16; ++q) {
      float4 w4 = wreg[q];
      a += w4.x * cs[dd][q * 4 + 0] + w4.y * cs[dd][q * 4 + 1]
         + w4.z * cs[dd][q * 4 + 2] + w4.w * cs[dd][q * 4 + 3];
    }
    M[((size_t)b * OC + o) * HID + h * DK + dd] = a;
  }
}

// ---------------- K3b: WM[b,o,c] = sum_hd M[b,o,hd] * Wq[hd,c]  (bf16 out) ----------------
__global__ __launch_bounds__(256) void k3b_fold_q(
    const float* __restrict__ M, const float* __restrict__ w_qkv,
    short* __restrict__ WM)
{
  const int ob = blockIdx.x, cb = blockIdx.y, b = blockIdx.z;
  const int o = ob * 32 + (threadIdx.x >> 3);
  const int c0 = cb * 32 + (threadIdx.x & 7) * 4;
  const float* Mrow = M + ((size_t)b * OC + o) * HID;
  float ax = 0.f, ay = 0.f, az = 0.f, aw = 0.f;
  for (int hd = 0; hd < HID; ++hd) {
    float m = Mrow[hd];
    float4 w4 = *(const float4*)&w_qkv[(size_t)hd * CIN + c0];
    ax += m * w4.x; ay += m * w4.y; az += m * w4.z; aw += m * w4.w;
  }
  short r[4] = {f2bf(ax), f2bf(ay), f2bf(az), f2bf(aw)};
  *(uint2*)(WM + ((size_t)b * OC + o) * CIN + c0) = *(uint2*)r;
}

// ---------------- K4: out[b,o,n] = sum_c WM[b,o,c]*imgT[b,n,c] + b_out[o] (MFMA) ----------------
__global__ __launch_bounds__(256) void k4_mfma(
    const short* __restrict__ WM, const short* __restrict__ imgT,
    const float* __restrict__ b_out, float* __restrict__ out)
{
  const int nt = blockIdx.x;   // 64 tiles of 64 n
  const int b = blockIdx.y;
  const int tid = threadIdx.x, w = tid >> 6, l = tid & 63;
  const int l15 = l & 15, l4 = l >> 4;
  const int n0 = nt * 64;

  __shared__ __align__(16) char sm4[40960];
  char* wmt = sm4;           // [256 o][64 c] bf16 swizzled
  char* xt  = sm4 + 32768;   // [64 n][64 c]

  f32x4 acc[4][4];
#pragma unroll
  for (int i = 0; i < 4; ++i)
#pragma unroll
    for (int j = 0; j < 4; ++j) acc[i][j] = (f32x4){0.f, 0.f, 0.f, 0.f};

  const int sr = tid >> 3, c8 = tid & 7;
  for (int ct = 0; ct < 4; ++ct) {
#pragma unroll
    for (int it = 0; it < 8; ++it) {
      int r = sr + it * 32;
      uint4 wv = *(const uint4*)(WM + ((size_t)b * OC + r) * CIN + ct * 64 + c8 * 8);
      *(uint4*)(wmt + r * 128 + ((c8 * 16) ^ ((r & 7) << 4))) = wv;
    }
#pragma unroll
    for (int it = 0; it < 2; ++it) {
      int nn = sr + it * 32;
      uint4 xv = *(const uint4*)(imgT + ((size_t)b * NSP + n0 + nn) * CIN + ct * 64 + c8 * 8);
      *(uint4*)(xt + nn * 128 + ((c8 * 16) ^ ((nn & 7) << 4))) = xv;
    }
    __syncthreads();
#pragma unroll
    for (int kk = 0; kk < 2; ++kk) {
      bf16x8 bfr[4];
#pragma unroll
      for (int tn = 0; tn < 4; ++tn) {
        int n = tn * 16 + l15;
        bfr[tn] = *(bf16x8*)(xt + n * 128 + ((kk * 64 + l4 * 16) ^ ((n & 7) << 4)));
      }
#pragma unroll
      for (int to = 0; to < 4; ++to) {
        int o = w * 64 + to * 16 + l15;
        bf16x8 a = *(bf16x8*)(wmt + o * 128 + ((kk * 64 + l4 * 16) ^ ((o & 7) << 4)));
#pragma unroll
        for (int tn = 0; tn < 4; ++tn)
          acc[to][tn] = __builtin_amdgcn_mfma_f32_16x16x32_bf16(a, bfr[tn], acc[to][tn], 0, 0, 0);
      }
    }
    __syncthreads();
  }
#pragma unroll
  for (int to = 0; to < 4; ++to) {
#pragma unroll
    for (int rg = 0; rg < 4; ++rg) {
      int o = w * 64 + to * 16 + l4 * 4 + rg;
      float bo = b_out[o];
#pragma unroll
      for (int tn = 0; tn < 4; ++tn) {
        int n = n0 + tn * 16 + l15;
        out[((size_t)b * OC + o) * NSP + n] = acc[to][tn][rg] + bo;
      }
    }
  }
}

extern "C" void kernel_launch(void* const* d_in, const int* in_sizes, int n_in,
                              void* d_out, int out_size, void* d_ws, size_t ws_size,
                              hipStream_t stream) {
  (void)in_sizes; (void)n_in; (void)out_size; (void)ws_size;
  const float* img   = (const float*)d_in[0];
  const float* w_qkv = (const float*)d_in[1];
  const float* w_out = (const float*)d_in[2];
  const float* b_out = (const float*)d_in[3];
  float* out = (float*)d_out;

  char* ws = (char*)d_ws;
  short* imgT     = (short*)ws;                   // 16,777,216 B
  short* wkv      = (short*)(ws + 16777216);      //    524,288 B
  float* ctx_part = (float*)(ws + 17301504);      //  8,388,608 B
  float* z_part   = (float*)(ws + 25690112);      //    131,072 B
  float* ctxn     = (float*)(ws + 25821184);      //  1,048,576 B
  float* Mbuf     = (float*)(ws + 26869760);      //  4,194,304 B
  short* WMbuf    = (short*)(ws + 31064064);      //  1,048,576 B  (end ~30.6 MB)

  p_transpose<<<dim3(64, 4, BATCH), 256, 0, stream>>>(img, imgT);
  p_weights<<<dim3(256), 256, 0, stream>>>(w_qkv, wkv);
  k1_mfma<<<dim3(NCH, HEADS, BATCH), 256, 0, stream>>>(imgT, wkv, ctx_part, z_part);
  k2_reduce<<<dim3(64), 256, 0, stream>>>(ctx_part, z_part, ctxn);
  k3a_fold_out<<<dim3(HEADS, BATCH), 256, 0, stream>>>(ctxn, w_out, Mbuf);
  k3b_fold_q<<<dim3(8, 8, BATCH), 256, 0, stream>>>(Mbuf, w_qkv, WMbuf);
  k4_mfma<<<dim3(64, BATCH), 256, 0, stream>>>(WMbuf, imgT, b_out, out);
}

// Round 3
// 142.478 us; speedup vs baseline: 3.9190x; 1.3473x over previous
//
#include <hip/hip_runtime.h>
#include <math.h>
#include <stdint.h>

// GSA linear attention — bf16 MFMA, pipelined k1 (weights-resident, counted-vmcnt dbuf).
// out[b] = WM[b] @ img[b] + b_out;  ctx[b,h] = softmax_n(k) @ v^T folded through w_out, Wq.

typedef __attribute__((ext_vector_type(8))) short bf16x8;
typedef __attribute__((ext_vector_type(4))) float f32x4;

#define BATCH 8
#define CIN 256
#define NSP 4096
#define HEADS 8
#define DK 64
#define HID 512
#define OC 256
#define NCH 4   // k1 chunks of 1024 n

#define VMCNT(n) asm volatile("s_waitcnt vmcnt(" #n ")" ::: "memory")
#define LGKM0()  asm volatile("s_waitcnt lgkmcnt(0)" ::: "memory")

__device__ __forceinline__ void barrier_fence() {
  asm volatile("" ::: "memory");
  __builtin_amdgcn_s_barrier();
  asm volatile("" ::: "memory");
}

__device__ __forceinline__ void gl16(const void* g, void* l) {
  __builtin_amdgcn_global_load_lds(
      (const __attribute__((address_space(1))) unsigned int*)g,
      (__attribute__((address_space(3))) unsigned int*)l, 16, 0, 0);
}

__device__ __forceinline__ short f2bf(float f) {
  union { float f; uint32_t u; } x; x.f = f;
  uint32_t r = x.u + 0x7fffu + ((x.u >> 16) & 1u);
  return (short)(r >> 16);
}

// ---------------- P: img [b][c][n] f32 -> imgT [b][n][c] bf16 ----------------
__global__ __launch_bounds__(256) void p_transpose(
    const float* __restrict__ img, short* __restrict__ imgT)
{
  const int ntile = blockIdx.x, ctile = blockIdx.y, b = blockIdx.z;
  __shared__ float t[64][65];
  const float* src = img + ((size_t)b * CIN + ctile * 64) * NSP + ntile * 64;
  for (int i = threadIdx.x; i < 4096; i += 256)
    t[i >> 6][i & 63] = src[(size_t)(i >> 6) * NSP + (i & 63)];
  __syncthreads();
  short* dst = imgT + ((size_t)b * NSP + ntile * 64) * CIN + ctile * 64;
  for (int i = threadIdx.x; i < 4096; i += 256) {
    int n = i >> 6, c = i & 63;
    dst[(size_t)n * CIN + c] = f2bf(t[c][n]);
  }
}

// ---------------- Pw: w_qkv k,v rows [512..1536) f32 -> bf16 [1024][256] ----------------
__global__ __launch_bounds__(256) void p_weights(
    const float* __restrict__ w_qkv, short* __restrict__ wkv)
{
  int i = blockIdx.x * 256 + threadIdx.x;
  const float* src = w_qkv + (size_t)HID * CIN;
  float4 v = ((const float4*)src)[i];
  short r[4] = {f2bf(v.x), f2bf(v.y), f2bf(v.z), f2bf(v.w)};
  *(uint2*)(wkv + (size_t)i * 4) = *(uint2*)r;
}

// ---------------- K1: weights-resident pipelined kv-proj + exp + ctx ----------------
// grid 256 (xcd-grouped decode), 512 thr = 8 waves, 1 block/CU.
// LDS: W [128r][512B] 64K | bufA [256n][128B] 32K | bufB 32K.  (128 KiB)
// Per t (256 n): 4 K-quarters (64 c) pipelined A/B with vmcnt(4); phase2 (ek@v^T)
// in two 128-n halves overlaid on the freed buffer.
__global__ __launch_bounds__(512, 2) void k1_mfma(
    const short* __restrict__ imgT, const short* __restrict__ wkv,
    float* __restrict__ ctx_part, float* __restrict__ z_part)
{
  const int bi = blockIdx.x;
  const int xcd = bi & 7, j = bi >> 3;
  const int h = j >> 2, gsub = j & 3;
  const int g = xcd + 8 * gsub;          // 32 (b,chunk) groups; 8 h share one XCD
  const int b = g >> 2, chunk = g & 3;

  const int tid = threadIdx.x, w = tid >> 6, l = tid & 63;
  const int l15 = l & 15, l4 = l >> 4;
  const int rowg = w & 1;   // 0: k rows (0..63), 1: v rows (64..127)
  const int ng = w >> 1;    // n-quarter 0..3 (64 n each)

  __shared__ __align__(16) char sm[131072];
  char* Wl = sm;                   // 65536
  char* bufA = sm + 65536;         // 32768
  char* bufB = sm + 98304;         // 32768

  // ---- prologue: issue W (8/thread) then first two quarters ----
  const int wrow_l = l >> 5, wcol = (l & 31) * 16;
#pragma unroll
  for (int r = 0; r < 8; ++r) {
    int row = w * 2 + r * 16 + wrow_l;
    int gr = (row < 64) ? (h * 64 + row) : (512 + h * 64 + (row - 64));
    const char* src = (const char*)wkv + (size_t)gr * 512 + (wcol ^ ((row & 7) << 4));
    gl16(src, Wl + (size_t)(w * 2 + r * 16) * 512);
  }
  const size_t ibase = (size_t)b * NSP * 512;  // bytes
  const int xrow_l = l >> 3, xcol = (l & 7) * 16;
  const int n00 = chunk * 1024;

  auto issue_x = [&](char* buf, int t, int q) {
    int nt0 = n00 + t * 256;
#pragma unroll
    for (int r = 0; r < 4; ++r) {
      int row = w * 8 + r * 64 + xrow_l;
      const char* src = (const char*)imgT + ibase + (size_t)(nt0 + row) * 512 + q * 128
                        + (xcol ^ ((row & 7) << 4));
      gl16(src, buf + (size_t)(w * 8 + r * 64) * 128);
    }
  };

  char* X = bufA; char* Y = bufB;
  issue_x(X, 0, 0);
  issue_x(Y, 0, 1);

  f32x4 acc2[2];
#pragma unroll
  for (int i = 0; i < 2; ++i) acc2[i] = (f32x4){0.f, 0.f, 0.f, 0.f};
  float zacc[4][4];
#pragma unroll
  for (int i = 0; i < 4; ++i)
#pragma unroll
    for (int jj = 0; jj < 4; ++jj) zacc[i][jj] = 0.f;

  f32x4 acc1[4][4];

  for (int t = 0; t < 4; ++t) {
#pragma unroll
    for (int i = 0; i < 4; ++i)
#pragma unroll
      for (int jj = 0; jj < 4; ++jj) acc1[i][jj] = (f32x4){0.f, 0.f, 0.f, 0.f};

    // ---- phase1: 4 quarters, A/B pipelined ----
#define P1_COMPUTE(BUF, Q)                                                        \
    {                                                                             \
      _Pragma("unroll")                                                           \
      for (int kk = 0; kk < 2; ++kk) {                                            \
        bf16x8 afr[4], bfr[4];                                                    \
        _Pragma("unroll")                                                         \
        for (int tr = 0; tr < 4; ++tr) {                                          \
          int row = rowg * 64 + tr * 16 + l15;                                    \
          afr[tr] = *(bf16x8*)(Wl + (size_t)row * 512 +                           \
                    (((Q) * 128 + kk * 64 + l4 * 16) ^ ((row & 7) << 4)));        \
        }                                                                         \
        _Pragma("unroll")                                                         \
        for (int tn = 0; tn < 4; ++tn) {                                          \
          int n = ng * 64 + tn * 16 + l15;                                        \
          bfr[tn] = *(bf16x8*)((BUF) + (size_t)n * 128 +                          \
                    ((kk * 64 + l4 * 16) ^ ((n & 7) << 4)));                      \
        }                                                                         \
        _Pragma("unroll")                                                         \
        for (int tr = 0; tr < 4; ++tr)                                            \
          _Pragma("unroll")                                                       \
          for (int tn = 0; tn < 4; ++tn)                                          \
            acc1[tr][tn] = __builtin_amdgcn_mfma_f32_16x16x32_bf16(               \
                afr[tr], bfr[tn], acc1[tr][tn], 0, 0, 0);                         \
      }                                                                           \
    }

    VMCNT(4); barrier_fence();
    P1_COMPUTE(X, 0);
    barrier_fence();
    issue_x(X, t, 2);

    VMCNT(4); barrier_fence();
    P1_COMPUTE(Y, 1);
    barrier_fence();
    issue_x(Y, t, 3);

    VMCNT(4); barrier_fence();
    P1_COMPUTE(X, 2);
    barrier_fence();

    VMCNT(0); barrier_fence();
    P1_COMPUTE(Y, 3);
    barrier_fence();
    if (t < 3) issue_x(Y, t + 1, 0);   // hidden under phase2

    // ---- phase2: ctx += exp(k) @ v^T over this t's 256 n, two 128-n halves in X ----
    char* ekb = X;            // [64 d][256 B]
    char* vbb = X + 16384;    // [64 e][256 B]
#pragma unroll
    for (int hf = 0; hf < 2; ++hf) {
      if ((ng >> 1) == hf) {
        char* dst = (rowg == 0) ? ekb : vbb;
#pragma unroll
        for (int tr = 0; tr < 4; ++tr) {
#pragma unroll
          for (int tn = 0; tn < 4; ++tn) {
            unsigned short us[4];
            f32x4 vv = acc1[tr][tn];
#pragma unroll
            for (int rg = 0; rg < 4; ++rg) {
              float f = vv[rg];
              if (rowg == 0) { f = __expf(f); zacc[tr][rg] += f; }
              us[rg] = (unsigned short)f2bf(f);
            }
            unsigned p01 = us[0] | ((unsigned)us[1] << 16);
            unsigned p23 = us[2] | ((unsigned)us[3] << 16);
            unsigned q01 = (unsigned)__shfl_xor((int)p01, 1, 64);
            unsigned q23 = (unsigned)__shfl_xor((int)p23, 1, 64);
            int nl = (ng & 1) * 64 + tn * 16 + l15;
            int nb = 2 * (nl & ~1);
            int r0 = tr * 16 + l4 * 4;
            unsigned w0, w1; int rga, rgb;
            if (!(l15 & 1)) {   // even lane writes rg 0,1
              w0 = (p01 & 0xffffu) | (q01 << 16);
              w1 = (p01 >> 16) | (q01 & 0xffff0000u);
              rga = 0; rgb = 1;
            } else {            // odd lane writes rg 2,3 (even's vals = q23)
              w0 = (q23 & 0xffffu) | (p23 << 16);
              w1 = (q23 >> 16) | (p23 & 0xffff0000u);
              rga = 2; rgb = 3;
            }
            int rowa = r0 + rga, rowb = r0 + rgb;
            *(unsigned*)(dst + (size_t)rowa * 256 + (nb ^ ((rowa & 7) << 4))) = w0;
            *(unsigned*)(dst + (size_t)rowb * 256 + (nb ^ ((rowb & 7) << 4))) = w1;
          }
        }
      }
      LGKM0(); barrier_fence();
      {
        const int dt = w >> 1, e0 = (w & 1) * 2;
#pragma unroll
        for (int kk = 0; kk < 4; ++kk) {
          int dr = dt * 16 + l15;
          bf16x8 a = *(bf16x8*)(ekb + (size_t)dr * 256 + ((kk * 64 + l4 * 16) ^ ((dr & 7) << 4)));
#pragma unroll
          for (int te = 0; te < 2; ++te) {
            int er = (e0 + te) * 16 + l15;
            bf16x8 bv = *(bf16x8*)(vbb + (size_t)er * 256 + ((kk * 64 + l4 * 16) ^ ((er & 7) << 4)));
            acc2[te] = __builtin_amdgcn_mfma_f32_16x16x32_bf16(a, bv, acc2[te], 0, 0, 0);
          }
        }
      }
      barrier_fence();
    }
    if (t < 3) issue_x(X, t + 1, 1);   // hidden under next t's q0 compute (from Y)
    { char* tmp = X; X = Y; Y = tmp; }
  }

  // ---- epilogue: ctx partial + z ----
  float* cp = ctx_part + ((size_t)(b * HEADS + h) * NCH + chunk) * (DK * DK);
#pragma unroll
  for (int te = 0; te < 2; ++te) {
#pragma unroll
    for (int rg = 0; rg < 4; ++rg) {
      int d = (w >> 1) * 16 + l4 * 4 + rg;
      int e = ((w & 1) * 2 + te) * 16 + l15;
      cp[d * 64 + e] = acc2[te][rg];
    }
  }
  float* zl = (float*)sm;   // reuse W region
  if (rowg == 0) {
#pragma unroll
    for (int tr = 0; tr < 4; ++tr) {
#pragma unroll
      for (int rg = 0; rg < 4; ++rg) {
        float z = zacc[tr][rg];
        z += __shfl_xor(z, 1, 64); z += __shfl_xor(z, 2, 64);
        z += __shfl_xor(z, 4, 64); z += __shfl_xor(z, 8, 64);
        if (l15 == 0) zl[ng * 64 + tr * 16 + l4 * 4 + rg] = z;
      }
    }
  }
  barrier_fence();
  if (tid < 64) {
    float z = zl[tid] + zl[64 + tid] + zl[128 + tid] + zl[192 + tid];
    z_part[((size_t)(b * HEADS + h) * NCH + chunk) * DK + tid] = z;
  }
}

// ---------------- K23: reduce+normalize ctx, fold w_out -> M ----------------
__global__ __launch_bounds__(256) void k23_fold(
    const float* __restrict__ ctx_part, const float* __restrict__ z_part,
    const float* __restrict__ w_out, float* __restrict__ M)
{
  const int h = blockIdx.x, b = blockIdx.y;
  const int bh = b * HEADS + h;
  __shared__ float cs[64][64];
  const int d = threadIdx.x >> 2, eb = threadIdx.x & 3;
  float s[16];
#pragma unroll
  for (int q = 0; q < 16; ++q) s[q] = 0.f;
  float z = 0.f;
  for (int ch = 0; ch < NCH; ++ch) {
    const float* p = ctx_part + ((size_t)bh * NCH + ch) * 4096 + d * 64 + eb * 16;
#pragma unroll
    for (int q = 0; q < 4; ++q) {
      float4 v = *(const float4*)&p[q * 4];
      s[q * 4 + 0] += v.x; s[q * 4 + 1] += v.y; s[q * 4 + 2] += v.z; s[q * 4 + 3] += v.w;
    }
    z += z_part[((size_t)bh * NCH + ch) * DK + d];
  }
  const float inv = 1.f / z;
#pragma unroll
  for (int q = 0; q < 16; ++q) cs[d][eb * 16 + q] = s[q] * inv;
  __syncthreads();
  const int o = threadIdx.x;
  float4 wreg[16];
#pragma unroll
  for (int q = 0; q < 16; ++q)
    wreg[q] = *(const float4*)&w_out[(size_t)o * HID + h * DK + q * 4];
  for (int dd = 0; dd < 64; ++dd) {
    float a = 0.f;
#pragma unroll
    for (int q = 0; q < 16; ++q) {
      float4 w4 = wreg[q];
      a += w4.x * cs[dd][q * 4 + 0] + w4.y * cs[dd][q * 4 + 1]
         + w4.z * cs[dd][q * 4 + 2] + w4.w * cs[dd][q * 4 + 3];
    }
    M[((size_t)b * OC + o) * HID + h * DK + dd] = a;
  }
}

// ---------------- K3b: WM[b,o,c] = sum_hd M[b,o,hd] * Wq[hd,c]  (bf16 out) ----------------
__global__ __launch_bounds__(256) void k3b_fold_q(
    const float* __restrict__ M, const float* __restrict__ w_qkv,
    short* __restrict__ WM)
{
  const int ob = blockIdx.x, cb = blockIdx.y, b = blockIdx.z;
  const int o = ob * 32 + (threadIdx.x >> 3);
  const int c0 = cb * 32 + (threadIdx.x & 7) * 4;
  const float* Mrow = M + ((size_t)b * OC + o) * HID;
  float ax = 0.f, ay = 0.f, az = 0.f, aw = 0.f;
  for (int hd = 0; hd < HID; ++hd) {
    float m = Mrow[hd];
    float4 w4 = *(const float4*)&w_qkv[(size_t)hd * CIN + c0];
    ax += m * w4.x; ay += m * w4.y; az += m * w4.z; aw += m * w4.w;
  }
  short r[4] = {f2bf(ax), f2bf(ay), f2bf(az), f2bf(aw)};
  *(uint2*)(WM + ((size_t)b * OC + o) * CIN + c0) = *(uint2*)r;
}

// ---------------- K4: out = WM @ imgT^T + b_out (MFMA, gload_lds) ----------------
// grid 256: b = i&7, nt = i>>3 (128-n tiles). 512 thr. LDS 48K -> 3 blocks/CU.
__global__ __launch_bounds__(512, 2) void k4_mfma(
    const short* __restrict__ WM, const short* __restrict__ imgT,
    const float* __restrict__ b_out, float* __restrict__ out)
{
  const int bi = blockIdx.x;
  const int b = bi & 7, nt = bi >> 3;
  const int n0 = nt * 128;
  const int tid = threadIdx.x, w = tid >> 6, l = tid & 63;
  const int l15 = l & 15, l4 = l >> 4;

  __shared__ __align__(16) char sm4[49152];
  char* wmt = sm4;            // [256 o][128 B]
  char* xt  = sm4 + 32768;    // [128 n][128 B]

  f32x4 acc[2][8];
#pragma unroll
  for (int i = 0; i < 2; ++i)
#pragma unroll
    for (int jj = 0; jj < 8; ++jj) acc[i][jj] = (f32x4){0.f, 0.f, 0.f, 0.f};

  const int srow_l = l >> 3, scol = (l & 7) * 16;
  const size_t wm_base = (size_t)b * OC * 512;           // bytes
  const size_t x_base = ((size_t)b * NSP + n0) * 512;    // bytes

  for (int ct = 0; ct < 4; ++ct) {
    barrier_fence();
#pragma unroll
    for (int r = 0; r < 4; ++r) {
      int row = w * 8 + r * 64 + srow_l;
      const char* src = (const char*)WM + wm_base + (size_t)row * 512 + ct * 128
                        + (scol ^ ((row & 7) << 4));
      gl16(src, wmt + (size_t)(w * 8 + r * 64) * 128);
    }
#pragma unroll
    for (int r = 0; r < 2; ++r) {
      int row = w * 8 + r * 64 + srow_l;
      const char* src = (const char*)imgT + x_base + (size_t)row * 512 + ct * 128
                        + (scol ^ ((row & 7) << 4));
      gl16(src, xt + (size_t)(w * 8 + r * 64) * 128);
    }
    VMCNT(0); barrier_fence();
#pragma unroll
    for (int kk = 0; kk < 2; ++kk) {
      bf16x8 afr[2]; bf16x8 bfr[8];
#pragma unroll
      for (int tr = 0; tr < 2; ++tr) {
        int o = w * 32 + tr * 16 + l15;
        afr[tr] = *(bf16x8*)(wmt + (size_t)o * 128 + ((kk * 64 + l4 * 16) ^ ((o & 7) << 4)));
      }
#pragma unroll
      for (int tn = 0; tn < 8; ++tn) {
        int n = tn * 16 + l15;
        bfr[tn] = *(bf16x8*)(xt + (size_t)n * 128 + ((kk * 64 + l4 * 16) ^ ((n & 7) << 4)));
      }
#pragma unroll
      for (int tr = 0; tr < 2; ++tr)
#pragma unroll
        for (int tn = 0; tn < 8; ++tn)
          acc[tr][tn] = __builtin_amdgcn_mfma_f32_16x16x32_bf16(afr[tr], bfr[tn], acc[tr][tn], 0, 0, 0);
    }
  }
#pragma unroll
  for (int tr = 0; tr < 2; ++tr) {
#pragma unroll
    for (int rg = 0; rg < 4; ++rg) {
      int o = w * 32 + tr * 16 + l4 * 4 + rg;
      float bo = b_out[o];
#pragma unroll
      for (int tn = 0; tn < 8; ++tn) {
        int n = n0 + tn * 16 + l15;
        out[((size_t)b * OC + o) * NSP + n] = acc[tr][tn][rg] + bo;
      }
    }
  }
}

extern "C" void kernel_launch(void* const* d_in, const int* in_sizes, int n_in,
                              void* d_out, int out_size, void* d_ws, size_t ws_size,
                              hipStream_t stream) {
  (void)in_sizes; (void)n_in; (void)out_size; (void)ws_size;
  const float* img   = (const float*)d_in[0];
  const float* w_qkv = (const float*)d_in[1];
  const float* w_out = (const float*)d_in[2];
  const float* b_out = (const float*)d_in[3];
  float* out = (float*)d_out;

  char* ws = (char*)d_ws;
  short* imgT     = (short*)ws;                   // 16,777,216
  short* wkv      = (short*)(ws + 16777216);      //    524,288
  float* ctx_part = (float*)(ws + 17301504);      //  4,194,304  (64 bh x 4 ch x 4096)
  float* z_part   = (float*)(ws + 21495808);      //     65,536
  float* Mbuf     = (float*)(ws + 21561344);      //  4,194,304
  short* WMbuf    = (short*)(ws + 25755648);      //  1,048,576  (end ~26.8 MB)

  p_transpose<<<dim3(64, 4, BATCH), 256, 0, stream>>>(img, imgT);
  p_weights<<<dim3(256), 256, 0, stream>>>(w_qkv, wkv);
  k1_mfma<<<dim3(256), 512, 0, stream>>>(imgT, wkv, ctx_part, z_part);
  k23_fold<<<dim3(HEADS, BATCH), 256, 0, stream>>>(ctx_part, z_part, w_out, Mbuf);
  k3b_fold_q<<<dim3(8, 8, BATCH), 256, 0, stream>>>(Mbuf, w_qkv, WMbuf);
  k4_mfma<<<dim3(256), 512, 0, stream>>>(WMbuf, imgT, b_out, out);
}

// Round 4
// 121.604 us; speedup vs baseline: 4.5917x; 1.1717x over previous
//
#include <hip/hip_runtime.h>
#include <math.h>
#include <stdint.h>

// GSA linear attention — bf16 MFMA. k1: W-in-registers, 3-buffer rotating LDS
// pipeline, counted vmcnt. k3b: MFMA fold. out[b] = WM[b] @ img[b] + b_out.

typedef __attribute__((ext_vector_type(8))) short bf16x8;
typedef __attribute__((ext_vector_type(4))) float f32x4;

#define BATCH 8
#define CIN 256
#define NSP 4096
#define HEADS 8
#define DK 64
#define HID 512
#define OC 256
#define NCH 4   // k1 chunks of 1024 n
#define NT 4    // 256-n tiles per chunk

#define VMCNT(n) asm volatile("s_waitcnt vmcnt(" #n ")" ::: "memory")
#define LGKM0()  asm volatile("s_waitcnt lgkmcnt(0)" ::: "memory")

__device__ __forceinline__ void barrier_fence() {
  asm volatile("" ::: "memory");
  __builtin_amdgcn_s_barrier();
  asm volatile("" ::: "memory");
}

__device__ __forceinline__ void gl16(const void* g, void* l) {
  __builtin_amdgcn_global_load_lds(
      (const __attribute__((address_space(1))) unsigned int*)g,
      (__attribute__((address_space(3))) unsigned int*)l, 16, 0, 0);
}

__device__ __forceinline__ short f2bf(float f) {
  union { float f; uint32_t u; } x; x.f = f;
  uint32_t r = x.u + 0x7fffu + ((x.u >> 16) & 1u);
  return (short)(r >> 16);
}

// ---------------- P: img [b][c][n] f32 -> imgT [b][n][c] bf16 (vectorized) ----------------
__global__ __launch_bounds__(256) void p_transpose(
    const float* __restrict__ img, short* __restrict__ imgT)
{
  const int ntile = blockIdx.x, ctile = blockIdx.y, b = blockIdx.z;
  __shared__ float t[64][65];
  const float* src = img + ((size_t)b * CIN + ctile * 64) * NSP + ntile * 64;
#pragma unroll
  for (int k = 0; k < 4; ++k) {
    int i = threadIdx.x + k * 256;          // 1024 float4s
    int c = i >> 4, n4 = (i & 15) * 4;
    float4 v = *(const float4*)&src[(size_t)c * NSP + n4];
    t[c][n4 + 0] = v.x; t[c][n4 + 1] = v.y; t[c][n4 + 2] = v.z; t[c][n4 + 3] = v.w;
  }
  __syncthreads();
  short* dst = imgT + ((size_t)b * NSP + ntile * 64) * CIN + ctile * 64;
#pragma unroll
  for (int k = 0; k < 4; ++k) {
    int j = threadIdx.x + k * 256;
    int n = j >> 4, c4 = (j & 15) * 4;
    short r[4] = {f2bf(t[c4 + 0][n]), f2bf(t[c4 + 1][n]),
                  f2bf(t[c4 + 2][n]), f2bf(t[c4 + 3][n])};
    *(uint2*)&dst[(size_t)n * CIN + c4] = *(uint2*)r;
  }
}

// ---------------- Pw: w_qkv k,v rows [512..1536) f32 -> bf16 [1024][256] ----------------
__global__ __launch_bounds__(256) void p_weights(
    const float* __restrict__ w_qkv, short* __restrict__ wkv)
{
  int i = blockIdx.x * 256 + threadIdx.x;
  const float* src = w_qkv + (size_t)HID * CIN;
  float4 v = ((const float4*)src)[i];
  short r[4] = {f2bf(v.x), f2bf(v.y), f2bf(v.z), f2bf(v.w)};
  *(uint2*)(wkv + (size_t)i * 4) = *(uint2*)r;
}

// ---------------- PwT: q rows of w_qkv [512][256] f32 -> WqT [256 c][512 hd] bf16 ----------------
__global__ __launch_bounds__(256) void p_wqT(
    const float* __restrict__ w_qkv, short* __restrict__ wqT)
{
  const int hdt = blockIdx.x, ct = blockIdx.y;   // 8 x 4
  __shared__ float t[64][65];
  for (int i = threadIdx.x; i < 4096; i += 256) {
    int r = i >> 6, cc = i & 63;
    t[r][cc] = w_qkv[(size_t)(hdt * 64 + r) * CIN + ct * 64 + cc];
  }
  __syncthreads();
#pragma unroll
  for (int k = 0; k < 4; ++k) {
    int j = threadIdx.x + k * 256;
    int c = j >> 4, h4 = (j & 15) * 4;
    short r[4] = {f2bf(t[h4 + 0][c]), f2bf(t[h4 + 1][c]),
                  f2bf(t[h4 + 2][c]), f2bf(t[h4 + 3][c])};
    *(uint2*)&wqT[(size_t)(ct * 64 + c) * HID + hdt * 64 + h4] = *(uint2*)r;
  }
}

// ---------------- K1: W-in-regs pipelined kv-proj + exp + ctx ----------------
// grid 256 (xcd-grouped), 512 thr = 8 waves. LDS: 3 x 32K rotating buffers.
// Waves: rg2 = w&3 (32-row group: 0,1=k 2,3=v), nh = w>>2 (128-n half).
__global__ __launch_bounds__(512, 2) void k1_mfma(
    const short* __restrict__ imgT, const short* __restrict__ wkv,
    float* __restrict__ ctx_part, float* __restrict__ z_part)
{
  const int bi = blockIdx.x;
  const int xcd = bi & 7, j = bi >> 3;
  const int h = j >> 2, gsub = j & 3;
  const int g = xcd + 8 * gsub;
  const int b = g >> 2, chunk = g & 3;

  const int tid = threadIdx.x, w = tid >> 6, l = tid & 63;
  const int l15 = l & 15, l4 = l >> 4;
  const int rg2 = w & 3, nh = w >> 2;

  __shared__ __align__(16) char sm[98304];
  char* pA = sm;
  char* pB = sm + 32768;
  char* pC = sm + 65536;

  // W fragments in registers: rows rg2*32 + tr*16 + l15, full K=256
  bf16x8 wreg[2][4][2];
#pragma unroll
  for (int tr = 0; tr < 2; ++tr) {
    int row = rg2 * 32 + tr * 16 + l15;
    int gr = (row < 64) ? (h * 64 + row) : (512 + h * 64 + (row - 64));
    const char* base = (const char*)wkv + (size_t)gr * 512;
#pragma unroll
    for (int kq = 0; kq < 4; ++kq)
#pragma unroll
      for (int kk = 0; kk < 2; ++kk)
        wreg[tr][kq][kk] = *(const bf16x8*)(base + kq * 128 + kk * 64 + l4 * 16);
  }

  const size_t ibase = (size_t)b * NSP * 512;  // bytes
  const int xrow_l = l >> 3, xcol = (l & 7) * 16;
  const int n00 = chunk * 1024;

  auto issue_x = [&](char* buf, int t, int q) {
    int nt0 = n00 + t * 256;
#pragma unroll
    for (int r = 0; r < 4; ++r) {
      int row = w * 8 + r * 64 + xrow_l;
      const char* src = (const char*)imgT + ibase + (size_t)(nt0 + row) * 512 + q * 128
                        + (xcol ^ ((row & 7) << 4));
      gl16(src, buf + (size_t)(w * 8 + r * 64) * 128);
    }
  };

  issue_x(pA, 0, 0);
  issue_x(pB, 0, 1);

  f32x4 acc2[2];
#pragma unroll
  for (int i = 0; i < 2; ++i) acc2[i] = (f32x4){0.f, 0.f, 0.f, 0.f};
  float zacc[2][4];
#pragma unroll
  for (int i = 0; i < 2; ++i)
#pragma unroll
    for (int jj = 0; jj < 4; ++jj) zacc[i][jj] = 0.f;

#define P1Q(BUF, Q)                                                       \
  {                                                                       \
    _Pragma("unroll")                                                     \
    for (int kk = 0; kk < 2; ++kk) {                                      \
      bf16x8 bfr[8];                                                      \
      _Pragma("unroll")                                                   \
      for (int tn = 0; tn < 8; ++tn) {                                    \
        int n = nh * 128 + tn * 16 + l15;                                 \
        bfr[tn] = *(bf16x8*)((BUF) + (size_t)n * 128 +                    \
                  ((kk * 64 + l4 * 16) ^ ((n & 7) << 4)));                \
      }                                                                   \
      _Pragma("unroll")                                                   \
      for (int tr = 0; tr < 2; ++tr)                                      \
        _Pragma("unroll")                                                 \
        for (int tn = 0; tn < 8; ++tn)                                    \
          acc1[tr][tn] = __builtin_amdgcn_mfma_f32_16x16x32_bf16(         \
              wreg[tr][Q][kk], bfr[tn], acc1[tr][tn], 0, 0, 0);           \
    }                                                                     \
  }

  for (int t = 0; t < NT; ++t) {
    const bool last = (t == NT - 1);
    f32x4 acc1[2][8];
#pragma unroll
    for (int i = 0; i < 2; ++i)
#pragma unroll
      for (int jj = 0; jj < 8; ++jj) acc1[i][jj] = (f32x4){0.f, 0.f, 0.f, 0.f};

    VMCNT(4); barrier_fence();
    issue_x(pC, t, 2);
    P1Q(pA, 0);

    VMCNT(4); barrier_fence();
    issue_x(pA, t, 3);
    P1Q(pB, 1);

    VMCNT(4); barrier_fence();
    if (!last) issue_x(pB, t + 1, 0);
    P1Q(pC, 2);

    if (last) { VMCNT(0); } else { VMCNT(4); }
    barrier_fence();
    if (!last) issue_x(pC, t + 1, 1);
    P1Q(pA, 3);

    // ---- phase2: ctx += exp(k) @ v^T, scratch = pA (ekb | vbb) ----
    barrier_fence();
#pragma unroll
    for (int hf = 0; hf < 2; ++hf) {
      if (nh == hf) {
        char* dst = (rg2 < 2) ? pA : (pA + 16384);
        const int rowb = (rg2 & 1) * 32;
#pragma unroll
        for (int tr = 0; tr < 2; ++tr) {
#pragma unroll
          for (int tn = 0; tn < 8; ++tn) {
            unsigned short us[4];
            f32x4 vv = acc1[tr][tn];
#pragma unroll
            for (int rg = 0; rg < 4; ++rg) {
              float f = vv[rg];
              if (rg2 < 2) { f = __expf(f); zacc[tr][rg] += f; }
              us[rg] = (unsigned short)f2bf(f);
            }
            unsigned p01 = us[0] | ((unsigned)us[1] << 16);
            unsigned p23 = us[2] | ((unsigned)us[3] << 16);
            unsigned q01 = (unsigned)__shfl_xor((int)p01, 1, 64);
            unsigned q23 = (unsigned)__shfl_xor((int)p23, 1, 64);
            int nl = tn * 16 + l15;
            int nb = 2 * (nl & ~1);
            int r0 = rowb + tr * 16 + l4 * 4;
            unsigned w0, w1; int rga, rgb;
            if (!(l15 & 1)) {
              w0 = (p01 & 0xffffu) | (q01 << 16);
              w1 = (p01 >> 16) | (q01 & 0xffff0000u);
              rga = 0; rgb = 1;
            } else {
              w0 = (q23 & 0xffffu) | (p23 << 16);
              w1 = (q23 >> 16) | (p23 & 0xffff0000u);
              rga = 2; rgb = 3;
            }
            int rowa = r0 + rga, rowbq = r0 + rgb;
            *(unsigned*)(dst + (size_t)rowa * 256 + (nb ^ ((rowa & 7) << 4))) = w0;
            *(unsigned*)(dst + (size_t)rowbq * 256 + (nb ^ ((rowbq & 7) << 4))) = w1;
          }
        }
      }
      LGKM0(); barrier_fence();
      {
        const int dt = w >> 1, e0 = (w & 1) * 2;
#pragma unroll
        for (int kk = 0; kk < 4; ++kk) {
          int dr = dt * 16 + l15;
          bf16x8 a = *(bf16x8*)(pA + (size_t)dr * 256 + ((kk * 64 + l4 * 16) ^ ((dr & 7) << 4)));
#pragma unroll
          for (int te = 0; te < 2; ++te) {
            int er = (e0 + te) * 16 + l15;
            bf16x8 bv = *(bf16x8*)(pA + 16384 + (size_t)er * 256 +
                                   ((kk * 64 + l4 * 16) ^ ((er & 7) << 4)));
            acc2[te] = __builtin_amdgcn_mfma_f32_16x16x32_bf16(a, bv, acc2[te], 0, 0, 0);
          }
        }
      }
      if (hf == 0) barrier_fence();
    }
    { char* tmp = pA; pA = pB; pB = pC; pC = tmp; }
  }

  // ---- epilogue ----
  float* cp = ctx_part + ((size_t)(b * HEADS + h) * NCH + chunk) * (DK * DK);
#pragma unroll
  for (int te = 0; te < 2; ++te) {
#pragma unroll
    for (int rg = 0; rg < 4; ++rg) {
      int d = (w >> 1) * 16 + l4 * 4 + rg;
      int e = ((w & 1) * 2 + te) * 16 + l15;
      cp[d * 64 + e] = acc2[te][rg];
    }
  }
  barrier_fence();
  float* zl = (float*)sm;
  if (rg2 < 2) {
#pragma unroll
    for (int tr = 0; tr < 2; ++tr) {
#pragma unroll
      for (int rg = 0; rg < 4; ++rg) {
        float z = zacc[tr][rg];
        z += __shfl_xor(z, 1, 64); z += __shfl_xor(z, 2, 64);
        z += __shfl_xor(z, 4, 64); z += __shfl_xor(z, 8, 64);
        if (l15 == 0) zl[nh * 64 + rg2 * 32 + tr * 16 + l4 * 4 + rg] = z;
      }
    }
  }
  LGKM0(); barrier_fence();
  if (tid < 64)
    z_part[((size_t)(b * HEADS + h) * NCH + chunk) * DK + tid] = zl[tid] + zl[64 + tid];
}

// ---------------- K23: reduce+normalize ctx, fold w_out -> M (bf16) ----------------
__global__ __launch_bounds__(256) void k23_fold(
    const float* __restrict__ ctx_part, const float* __restrict__ z_part,
    const float* __restrict__ w_out, short* __restrict__ M)
{
  const int h = blockIdx.x, b = blockIdx.y;
  const int bh = b * HEADS + h;
  __shared__ float cs[64][64];
  const int d = threadIdx.x >> 2, eb = threadIdx.x & 3;
  float s[16];
#pragma unroll
  for (int q = 0; q < 16; ++q) s[q] = 0.f;
  float z = 0.f;
  for (int ch = 0; ch < NCH; ++ch) {
    const float* p = ctx_part + ((size_t)bh * NCH + ch) * 4096 + d * 64 + eb * 16;
#pragma unroll
    for (int q = 0; q < 4; ++q) {
      float4 v = *(const float4*)&p[q * 4];
      s[q * 4 + 0] += v.x; s[q * 4 + 1] += v.y; s[q * 4 + 2] += v.z; s[q * 4 + 3] += v.w;
    }
    z += z_part[((size_t)bh * NCH + ch) * DK + d];
  }
  const float inv = 1.f / z;
#pragma unroll
  for (int q = 0; q < 16; ++q) cs[d][eb * 16 + q] = s[q] * inv;
  __syncthreads();
  const int o = threadIdx.x;
  float4 wreg[16];
#pragma unroll
  for (int q = 0; q < 16; ++q)
    wreg[q] = *(const float4*)&w_out[(size_t)o * HID + h * DK + q * 4];
  for (int dd = 0; dd < 64; ++dd) {
    float a = 0.f;
#pragma unroll
    for (int q = 0; q < 16; ++q) {
      float4 w4 = wreg[q];
      a += w4.x * cs[dd][q * 4 + 0] + w4.y * cs[dd][q * 4 + 1]
         + w4.z * cs[dd][q * 4 + 2] + w4.w * cs[dd][q * 4 + 3];
    }
    M[((size_t)b * OC + o) * HID + h * DK + dd] = f2bf(a);
  }
}

// ---------------- K3b: WM[b,o,c] = M[b,o,:] @ WqT[c,:]  (MFMA, bf16) ----------------
// grid (4 ctiles of 64, 8 b), 512 thr. K=512 in 8 steps of 64.
__global__ __launch_bounds__(512) void k3b_mfma(
    const short* __restrict__ M, const short* __restrict__ wqT,
    short* __restrict__ WM)
{
  const int ct = blockIdx.x, b = blockIdx.y;
  const int tid = threadIdx.x, w = tid >> 6, l = tid & 63;
  const int l15 = l & 15, l4 = l >> 4;

  __shared__ __align__(16) char sm3[40960];
  char* At = sm3;           // [256 o][128 B]
  char* Bt = sm3 + 32768;   // [64 c][128 B]

  f32x4 acc[4][2];
#pragma unroll
  for (int i = 0; i < 4; ++i)
#pragma unroll
    for (int jj = 0; jj < 2; ++jj) acc[i][jj] = (f32x4){0.f, 0.f, 0.f, 0.f};

  const int srow = tid >> 3, scol = (tid & 7) * 16;
  for (int st = 0; st < 8; ++st) {
#pragma unroll
    for (int p = 0; p < 4; ++p) {
      int row = p * 64 + srow;
      const char* src = (const char*)M + ((size_t)b * OC + row) * 1024 + st * 128
                        + (scol ^ ((row & 7) << 4));
      gl16(src, At + (size_t)(p * 64 + w * 8) * 128);
    }
    {
      int row = srow;
      const char* src = (const char*)wqT + (size_t)(ct * 64 + row) * 1024 + st * 128
                        + (scol ^ ((row & 7) << 4));
      gl16(src, Bt + (size_t)(w * 8) * 128);
    }
    VMCNT(0); barrier_fence();
#pragma unroll
    for (int kk = 0; kk < 2; ++kk) {
      bf16x8 afr[4], bfr[2];
#pragma unroll
      for (int tr = 0; tr < 4; ++tr) {
        int o = (w >> 1) * 64 + tr * 16 + l15;
        afr[tr] = *(bf16x8*)(At + (size_t)o * 128 + ((kk * 64 + l4 * 16) ^ ((o & 7) << 4)));
      }
#pragma unroll
      for (int tn = 0; tn < 2; ++tn) {
        int c = (w & 1) * 32 + tn * 16 + l15;
        bfr[tn] = *(bf16x8*)(Bt + (size_t)c * 128 + ((kk * 64 + l4 * 16) ^ ((c & 7) << 4)));
      }
#pragma unroll
      for (int tr = 0; tr < 4; ++tr)
#pragma unroll
        for (int tn = 0; tn < 2; ++tn)
          acc[tr][tn] = __builtin_amdgcn_mfma_f32_16x16x32_bf16(afr[tr], bfr[tn], acc[tr][tn], 0, 0, 0);
    }
    barrier_fence();
  }
#pragma unroll
  for (int tr = 0; tr < 4; ++tr) {
#pragma unroll
    for (int tn = 0; tn < 2; ++tn) {
#pragma unroll
      for (int rg = 0; rg < 4; ++rg) {
        int o = (w >> 1) * 64 + tr * 16 + l4 * 4 + rg;
        int c = ct * 64 + (w & 1) * 32 + tn * 16 + l15;
        WM[((size_t)b * OC + o) * CIN + c] = f2bf(acc[tr][tn][rg]);
      }
    }
  }
}

// ---------------- K4: out = WM @ imgT^T + b_out (MFMA, gload_lds) ----------------
__global__ __launch_bounds__(512, 2) void k4_mfma(
    const short* __restrict__ WM, const short* __restrict__ imgT,
    const float* __restrict__ b_out, float* __restrict__ out)
{
  const int bi = blockIdx.x;
  const int b = bi & 7, nt = bi >> 3;
  const int n0 = nt * 128;
  const int tid = threadIdx.x, w = tid >> 6, l = tid & 63;
  const int l15 = l & 15, l4 = l >> 4;

  __shared__ __align__(16) char sm4[49152];
  char* wmt = sm4;            // [256 o][128 B]
  char* xt  = sm4 + 32768;    // [128 n][128 B]

  f32x4 acc[2][8];
#pragma unroll
  for (int i = 0; i < 2; ++i)
#pragma unroll
    for (int jj = 0; jj < 8; ++jj) acc[i][jj] = (f32x4){0.f, 0.f, 0.f, 0.f};

  const int srow_l = l >> 3, scol = (l & 7) * 16;
  const size_t wm_base = (size_t)b * OC * 512;
  const size_t x_base = ((size_t)b * NSP + n0) * 512;

  for (int ct = 0; ct < 4; ++ct) {
    barrier_fence();
#pragma unroll
    for (int r = 0; r < 4; ++r) {
      int row = w * 8 + r * 64 + srow_l;
      const char* src = (const char*)WM + wm_base + (size_t)row * 512 + ct * 128
                        + (scol ^ ((row & 7) << 4));
      gl16(src, wmt + (size_t)(w * 8 + r * 64) * 128);
    }
#pragma unroll
    for (int r = 0; r < 2; ++r) {
      int row = w * 8 + r * 64 + srow_l;
      const char* src = (const char*)imgT + x_base + (size_t)row * 512 + ct * 128
                        + (scol ^ ((row & 7) << 4));
      gl16(src, xt + (size_t)(w * 8 + r * 64) * 128);
    }
    VMCNT(0); barrier_fence();
#pragma unroll
    for (int kk = 0; kk < 2; ++kk) {
      bf16x8 afr[2]; bf16x8 bfr[8];
#pragma unroll
      for (int tr = 0; tr < 2; ++tr) {
        int o = w * 32 + tr * 16 + l15;
        afr[tr] = *(bf16x8*)(wmt + (size_t)o * 128 + ((kk * 64 + l4 * 16) ^ ((o & 7) << 4)));
      }
#pragma unroll
      for (int tn = 0; tn < 8; ++tn) {
        int n = tn * 16 + l15;
        bfr[tn] = *(bf16x8*)(xt + (size_t)n * 128 + ((kk * 64 + l4 * 16) ^ ((n & 7) << 4)));
      }
#pragma unroll
      for (int tr = 0; tr < 2; ++tr)
#pragma unroll
        for (int tn = 0; tn < 8; ++tn)
          acc[tr][tn] = __builtin_amdgcn_mfma_f32_16x16x32_bf16(afr[tr], bfr[tn], acc[tr][tn], 0, 0, 0);
    }
  }
#pragma unroll
  for (int tr = 0; tr < 2; ++tr) {
#pragma unroll
    for (int rg = 0; rg < 4; ++rg) {
      int o = w * 32 + tr * 16 + l4 * 4 + rg;
      float bo = b_out[o];
#pragma unroll
      for (int tn = 0; tn < 8; ++tn) {
        int n = n0 + tn * 16 + l15;
        out[((size_t)b * OC + o) * NSP + n] = acc[tr][tn][rg] + bo;
      }
    }
  }
}

extern "C" void kernel_launch(void* const* d_in, const int* in_sizes, int n_in,
                              void* d_out, int out_size, void* d_ws, size_t ws_size,
                              hipStream_t stream) {
  (void)in_sizes; (void)n_in; (void)out_size; (void)ws_size;
  const float* img   = (const float*)d_in[0];
  const float* w_qkv = (const float*)d_in[1];
  const float* w_out = (const float*)d_in[2];
  const float* b_out = (const float*)d_in[3];
  float* out = (float*)d_out;

  char* ws = (char*)d_ws;
  short* imgT     = (short*)ws;                   // 16,777,216
  short* wkv      = (short*)(ws + 16777216);      //    524,288
  short* wqT      = (short*)(ws + 17301504);      //    262,144
  float* ctx_part = (float*)(ws + 17563648);      //  4,194,304
  float* z_part   = (float*)(ws + 21757952);      //     65,536
  short* Mbuf     = (short*)(ws + 21823488);      //  2,097,152
  short* WMbuf    = (short*)(ws + 23920640);      //  1,048,576  (end ~25 MB)

  p_transpose<<<dim3(64, 4, BATCH), 256, 0, stream>>>(img, imgT);
  p_weights<<<dim3(256), 256, 0, stream>>>(w_qkv, wkv);
  p_wqT<<<dim3(8, 4), 256, 0, stream>>>(w_qkv, wqT);
  k1_mfma<<<dim3(256), 512, 0, stream>>>(imgT, wkv, ctx_part, z_part);
  k23_fold<<<dim3(HEADS, BATCH), 256, 0, stream>>>(ctx_part, z_part, w_out, Mbuf);
  k3b_mfma<<<dim3(4, 8), 512, 0, stream>>>(Mbuf, wqT, WMbuf);
  k4_mfma<<<dim3(256), 512, 0, stream>>>(WMbuf, imgT, b_out, out);
}

// Round 5
// 116.773 us; speedup vs baseline: 4.7816x; 1.0414x over previous
//
#include <hip/hip_runtime.h>
#include <math.h>
#include <stdint.h>

// GSA linear attention — bf16 MFMA. k1: 4-wave blocks, 2 blocks/CU, W-in-regs,
// 3x16KB rotating quarter buffers + dedicated 32KB phase2 scratch, counted vmcnt.
// k4: WM-in-regs streaming GEMM. out[b] = WM[b] @ img[b] + b_out.

typedef __attribute__((ext_vector_type(8))) short bf16x8;
typedef __attribute__((ext_vector_type(4))) float f32x4;

#define BATCH 8
#define CIN 256
#define NSP 4096
#define HEADS 8
#define DK 64
#define HID 512
#define OC 256
#define NCH 8   // k1 chunks of 512 n
#define NT 4    // 128-n tiles per chunk

#define VMCNT(n) asm volatile("s_waitcnt vmcnt(" #n ")" ::: "memory")
#define LGKM0()  asm volatile("s_waitcnt lgkmcnt(0)" ::: "memory")

__device__ __forceinline__ void barrier_fence() {
  asm volatile("" ::: "memory");
  __builtin_amdgcn_s_barrier();
  asm volatile("" ::: "memory");
}

__device__ __forceinline__ void gl16(const void* g, void* l) {
  __builtin_amdgcn_global_load_lds(
      (const __attribute__((address_space(1))) unsigned int*)g,
      (__attribute__((address_space(3))) unsigned int*)l, 16, 0, 0);
}

__device__ __forceinline__ short f2bf(float f) {
  union { float f; uint32_t u; } x; x.f = f;
  uint32_t r = x.u + 0x7fffu + ((x.u >> 16) & 1u);
  return (short)(r >> 16);
}

// ---------------- P: img [b][c][n] f32 -> imgT [b][n][c] bf16 ----------------
__global__ __launch_bounds__(256) void p_transpose(
    const float* __restrict__ img, short* __restrict__ imgT)
{
  const int ntile = blockIdx.x, ctile = blockIdx.y, b = blockIdx.z;
  __shared__ float t[64][65];
  const float* src = img + ((size_t)b * CIN + ctile * 64) * NSP + ntile * 64;
#pragma unroll
  for (int k = 0; k < 4; ++k) {
    int i = threadIdx.x + k * 256;
    int c = i >> 4, n4 = (i & 15) * 4;
    float4 v = *(const float4*)&src[(size_t)c * NSP + n4];
    t[c][n4 + 0] = v.x; t[c][n4 + 1] = v.y; t[c][n4 + 2] = v.z; t[c][n4 + 3] = v.w;
  }
  __syncthreads();
  short* dst = imgT + ((size_t)b * NSP + ntile * 64) * CIN + ctile * 64;
#pragma unroll
  for (int k = 0; k < 4; ++k) {
    int j = threadIdx.x + k * 256;
    int n = j >> 4, c4 = (j & 15) * 4;
    short r[4] = {f2bf(t[c4 + 0][n]), f2bf(t[c4 + 1][n]),
                  f2bf(t[c4 + 2][n]), f2bf(t[c4 + 3][n])};
    *(uint2*)&dst[(size_t)n * CIN + c4] = *(uint2*)r;
  }
}

// ---------------- Pw: w_qkv k,v rows -> bf16 [1024][256] ----------------
__global__ __launch_bounds__(256) void p_weights(
    const float* __restrict__ w_qkv, short* __restrict__ wkv)
{
  int i = blockIdx.x * 256 + threadIdx.x;
  const float* src = w_qkv + (size_t)HID * CIN;
  float4 v = ((const float4*)src)[i];
  short r[4] = {f2bf(v.x), f2bf(v.y), f2bf(v.z), f2bf(v.w)};
  *(uint2*)(wkv + (size_t)i * 4) = *(uint2*)r;
}

// ---------------- PwT: q rows f32 -> WqT [256 c][512 hd] bf16 ----------------
__global__ __launch_bounds__(256) void p_wqT(
    const float* __restrict__ w_qkv, short* __restrict__ wqT)
{
  const int hdt = blockIdx.x, ct = blockIdx.y;
  __shared__ float t[64][65];
  for (int i = threadIdx.x; i < 4096; i += 256) {
    int r = i >> 6, cc = i & 63;
    t[r][cc] = w_qkv[(size_t)(hdt * 64 + r) * CIN + ct * 64 + cc];
  }
  __syncthreads();
#pragma unroll
  for (int k = 0; k < 4; ++k) {
    int j = threadIdx.x + k * 256;
    int c = j >> 4, h4 = (j & 15) * 4;
    short r[4] = {f2bf(t[h4 + 0][c]), f2bf(t[h4 + 1][c]),
                  f2bf(t[h4 + 2][c]), f2bf(t[h4 + 3][c])};
    *(uint2*)&wqT[(size_t)(ct * 64 + c) * HID + hdt * 64 + h4] = *(uint2*)r;
  }
}

// ---------------- K1: 4-wave pipelined kv-proj + exp + ctx ----------------
// grid 512 = (xcd-grouped: 8h per XCD share (b,ch)). 256 thr. LDS 80K -> 2 blocks/CU.
__global__ __launch_bounds__(256, 2) void k1_mfma(
    const short* __restrict__ imgT, const short* __restrict__ wkv,
    float* __restrict__ ctx_part, float* __restrict__ z_part)
{
  const int bi = blockIdx.x;
  const int x = bi & 7, m = bi >> 3;
  const int h = m & 7, g = (m >> 3) * 8 + x;   // g in [0,64)
  const int b = g >> 3, ch = g & 7;

  const int tid = threadIdx.x, w = tid >> 6, l = tid & 63;
  const int l15 = l & 15, l4 = l >> 4;

  __shared__ __align__(16) char sm[81920];
  char* scr = sm + 49152;   // ek [64][256B] | v [64][256B]

  // W in regs: wave w owns rows w*32 + tr*16 + l15 (w<2: k, w>=2: v)
  bf16x8 wreg[2][4][2];
#pragma unroll
  for (int tr = 0; tr < 2; ++tr) {
    int row = w * 32 + tr * 16 + l15;
    int gr = (row < 64) ? (h * 64 + row) : (512 + h * 64 + (row - 64));
    const char* base = (const char*)wkv + (size_t)gr * 512;
#pragma unroll
    for (int kq = 0; kq < 4; ++kq)
#pragma unroll
      for (int kk = 0; kk < 2; ++kk)
        wreg[tr][kq][kk] = *(const bf16x8*)(base + kq * 128 + kk * 64 + l4 * 16);
  }
  VMCNT(0);   // clean vmcnt bookkeeping before gl16 pipeline

  const char* ibase = (const char*)imgT + (size_t)b * NSP * 512 + (size_t)ch * 512 * 512;
  const int rowpart = w * 8 + (l >> 3);
  const int colswz = ((l & 7) * 16) ^ (((l >> 3) & 7) << 4);

  auto issue_x = [&](char* buf, int t, int q) {
#pragma unroll
    for (int r = 0; r < 4; ++r) {
      int row = rowpart + r * 32;
      const char* src = ibase + (size_t)(t * 128 + row) * 512 + q * 128 + colswz;
      gl16(src, buf + (size_t)(w * 8 + r * 32) * 128);
    }
  };

  char* p0 = sm; char* p1 = sm + 16384; char* p2 = sm + 32768;
  issue_x(p0, 0, 0);
  issue_x(p1, 0, 1);

  f32x4 acc2[4];
#pragma unroll
  for (int i = 0; i < 4; ++i) acc2[i] = (f32x4){0.f, 0.f, 0.f, 0.f};
  float zacc[2][4];
#pragma unroll
  for (int i = 0; i < 2; ++i)
#pragma unroll
    for (int jj = 0; jj < 4; ++jj) zacc[i][jj] = 0.f;

#define P1Q(BUF, Q)                                                       \
  {                                                                       \
    _Pragma("unroll")                                                     \
    for (int kk = 0; kk < 2; ++kk) {                                      \
      bf16x8 bfr[8];                                                      \
      _Pragma("unroll")                                                   \
      for (int tn = 0; tn < 8; ++tn) {                                    \
        int n = tn * 16 + l15;                                            \
        bfr[tn] = *(bf16x8*)((BUF) + (size_t)n * 128 +                    \
                  ((kk * 64 + l4 * 16) ^ ((n & 7) << 4)));                \
      }                                                                   \
      __builtin_amdgcn_s_setprio(1);                                      \
      _Pragma("unroll")                                                   \
      for (int tr = 0; tr < 2; ++tr)                                      \
        _Pragma("unroll")                                                 \
        for (int tn = 0; tn < 8; ++tn)                                    \
          acc1[tr][tn] = __builtin_amdgcn_mfma_f32_16x16x32_bf16(         \
              wreg[tr][Q][kk], bfr[tn], acc1[tr][tn], 0, 0, 0);           \
      __builtin_amdgcn_s_setprio(0);                                      \
    }                                                                     \
  }

  for (int t = 0; t < NT; ++t) {
    const bool last = (t == NT - 1);
    f32x4 acc1[2][8];
#pragma unroll
    for (int i = 0; i < 2; ++i)
#pragma unroll
      for (int jj = 0; jj < 8; ++jj) acc1[i][jj] = (f32x4){0.f, 0.f, 0.f, 0.f};

    VMCNT(4); barrier_fence();
    issue_x(p2, t, 2);
    P1Q(p0, 0);

    VMCNT(4); barrier_fence();
    issue_x(p0, t, 3);
    P1Q(p1, 1);

    VMCNT(4); barrier_fence();
    if (!last) issue_x(p1, t + 1, 0);
    P1Q(p2, 2);

    if (last) { VMCNT(0); } else { VMCNT(4); }
    barrier_fence();
    if (!last) issue_x(p2, t + 1, 1);
    P1Q(p0, 3);

    // ---- phase2: all 4 waves write their 32 rows to scratch ----
    {
      char* dst = (w < 2) ? scr : (scr + 16384);
      const int rowb = (w & 1) * 32;
#pragma unroll
      for (int tr = 0; tr < 2; ++tr) {
#pragma unroll
        for (int tn = 0; tn < 8; ++tn) {
          unsigned short us[4];
          f32x4 vv = acc1[tr][tn];
#pragma unroll
          for (int rg = 0; rg < 4; ++rg) {
            float f = vv[rg];
            if (w < 2) { f = __expf(f); zacc[tr][rg] += f; }
            us[rg] = (unsigned short)f2bf(f);
          }
          unsigned p01 = us[0] | ((unsigned)us[1] << 16);
          unsigned p23 = us[2] | ((unsigned)us[3] << 16);
          unsigned q01 = (unsigned)__shfl_xor((int)p01, 1, 64);
          unsigned q23 = (unsigned)__shfl_xor((int)p23, 1, 64);
          int nl = tn * 16 + l15;
          int nb = 2 * (nl & ~1);
          int r0 = rowb + tr * 16 + l4 * 4;
          unsigned w0, w1; int rga, rgb;
          if (!(l15 & 1)) {
            w0 = (p01 & 0xffffu) | (q01 << 16);
            w1 = (p01 >> 16) | (q01 & 0xffff0000u);
            rga = 0; rgb = 1;
          } else {
            w0 = (q23 & 0xffffu) | (p23 << 16);
            w1 = (q23 >> 16) | (p23 & 0xffff0000u);
            rga = 2; rgb = 3;
          }
          int rowa = r0 + rga, rowbq = r0 + rgb;
          *(unsigned*)(dst + (size_t)rowa * 256 + (nb ^ ((rowa & 7) << 4))) = w0;
          *(unsigned*)(dst + (size_t)rowbq * 256 + (nb ^ ((rowbq & 7) << 4))) = w1;
        }
      }
    }
    LGKM0(); barrier_fence();
    // ---- ctx MFMA: wave w = d-tile, K = 128 n ----
#pragma unroll
    for (int kk = 0; kk < 4; ++kk) {
      int dr = w * 16 + l15;
      bf16x8 a = *(bf16x8*)(scr + (size_t)dr * 256 + ((kk * 64 + l4 * 16) ^ ((dr & 7) << 4)));
      __builtin_amdgcn_s_setprio(1);
#pragma unroll
      for (int te = 0; te < 4; ++te) {
        int er = te * 16 + l15;
        bf16x8 bv = *(bf16x8*)(scr + 16384 + (size_t)er * 256 +
                               ((kk * 64 + l4 * 16) ^ ((er & 7) << 4)));
        acc2[te] = __builtin_amdgcn_mfma_f32_16x16x32_bf16(a, bv, acc2[te], 0, 0, 0);
      }
      __builtin_amdgcn_s_setprio(0);
    }
    // no barrier needed: scratch next written after 4 more barriers
    { char* tmp = p0; p0 = p1; p1 = p2; p2 = tmp; }
  }

  // ---- epilogue ----
  float* cp = ctx_part + ((size_t)(b * HEADS + h) * NCH + ch) * (DK * DK);
#pragma unroll
  for (int te = 0; te < 4; ++te) {
#pragma unroll
    for (int rg = 0; rg < 4; ++rg) {
      int d = w * 16 + l4 * 4 + rg;
      int e = te * 16 + l15;
      cp[d * 64 + e] = acc2[te][rg];
    }
  }
  if (w < 2) {
#pragma unroll
    for (int tr = 0; tr < 2; ++tr) {
#pragma unroll
      for (int rg = 0; rg < 4; ++rg) {
        float z = zacc[tr][rg];
        z += __shfl_xor(z, 1, 64); z += __shfl_xor(z, 2, 64);
        z += __shfl_xor(z, 4, 64); z += __shfl_xor(z, 8, 64);
        if (l15 == 0) {
          int d = w * 32 + tr * 16 + l4 * 4 + rg;
          z_part[((size_t)(b * HEADS + h) * NCH + ch) * DK + d] = z;
        }
      }
    }
  }
}

// ---------------- K23: reduce+normalize ctx, fold w_out -> M (bf16) ----------------
__global__ __launch_bounds__(256) void k23_fold(
    const float* __restrict__ ctx_part, const float* __restrict__ z_part,
    const float* __restrict__ w_out, short* __restrict__ M)
{
  const int h = blockIdx.x, b = blockIdx.y;
  const int bh = b * HEADS + h;
  __shared__ float cs[64][64];
  const int d = threadIdx.x >> 2, eb = threadIdx.x & 3;
  float s[16];
#pragma unroll
  for (int q = 0; q < 16; ++q) s[q] = 0.f;
  float z = 0.f;
  for (int chh = 0; chh < NCH; ++chh) {
    const float* p = ctx_part + ((size_t)bh * NCH + chh) * 4096 + d * 64 + eb * 16;
#pragma unroll
    for (int q = 0; q < 4; ++q) {
      float4 v = *(const float4*)&p[q * 4];
      s[q * 4 + 0] += v.x; s[q * 4 + 1] += v.y; s[q * 4 + 2] += v.z; s[q * 4 + 3] += v.w;
    }
    z += z_part[((size_t)bh * NCH + chh) * DK + d];
  }
  const float inv = 1.f / z;
#pragma unroll
  for (int q = 0; q < 16; ++q) cs[d][eb * 16 + q] = s[q] * inv;
  __syncthreads();
  const int o = threadIdx.x;
  float4 wreg[16];
#pragma unroll
  for (int q = 0; q < 16; ++q)
    wreg[q] = *(const float4*)&w_out[(size_t)o * HID + h * DK + q * 4];
  for (int dd = 0; dd < 64; ++dd) {
    float a = 0.f;
#pragma unroll
    for (int q = 0; q < 16; ++q) {
      float4 w4 = wreg[q];
      a += w4.x * cs[dd][q * 4 + 0] + w4.y * cs[dd][q * 4 + 1]
         + w4.z * cs[dd][q * 4 + 2] + w4.w * cs[dd][q * 4 + 3];
    }
    M[((size_t)b * OC + o) * HID + h * DK + dd] = f2bf(a);
  }
}

// ---------------- K3b: WM[b,o,c] = M[b,o,:] @ WqT[c,:]  (MFMA) ----------------
__global__ __launch_bounds__(512) void k3b_mfma(
    const short* __restrict__ M, const short* __restrict__ wqT,
    short* __restrict__ WM)
{
  const int ct = blockIdx.x, b = blockIdx.y;
  const int tid = threadIdx.x, w = tid >> 6, l = tid & 63;
  const int l15 = l & 15, l4 = l >> 4;

  __shared__ __align__(16) char sm3[40960];
  char* At = sm3;           // [256 o][128 B]
  char* Bt = sm3 + 32768;   // [64 c][128 B]

  f32x4 acc[4][2];
#pragma unroll
  for (int i = 0; i < 4; ++i)
#pragma unroll
    for (int jj = 0; jj < 2; ++jj) acc[i][jj] = (f32x4){0.f, 0.f, 0.f, 0.f};

  const int srow = tid >> 3, scol = (tid & 7) * 16;
  for (int st = 0; st < 8; ++st) {
#pragma unroll
    for (int p = 0; p < 4; ++p) {
      int row = p * 64 + srow;
      const char* src = (const char*)M + ((size_t)b * OC + row) * 1024 + st * 128
                        + (scol ^ ((row & 7) << 4));
      gl16(src, At + (size_t)(p * 64 + w * 8) * 128);
    }
    {
      int row = srow;
      const char* src = (const char*)wqT + (size_t)(ct * 64 + row) * 1024 + st * 128
                        + (scol ^ ((row & 7) << 4));
      gl16(src, Bt + (size_t)(w * 8) * 128);
    }
    VMCNT(0); barrier_fence();
#pragma unroll
    for (int kk = 0; kk < 2; ++kk) {
      bf16x8 afr[4], bfr[2];
#pragma unroll
      for (int tr = 0; tr < 4; ++tr) {
        int o = (w >> 1) * 64 + tr * 16 + l15;
        afr[tr] = *(bf16x8*)(At + (size_t)o * 128 + ((kk * 64 + l4 * 16) ^ ((o & 7) << 4)));
      }
#pragma unroll
      for (int tn = 0; tn < 2; ++tn) {
        int c = (w & 1) * 32 + tn * 16 + l15;
        bfr[tn] = *(bf16x8*)(Bt + (size_t)c * 128 + ((kk * 64 + l4 * 16) ^ ((c & 7) << 4)));
      }
#pragma unroll
      for (int tr = 0; tr < 4; ++tr)
#pragma unroll
        for (int tn = 0; tn < 2; ++tn)
          acc[tr][tn] = __builtin_amdgcn_mfma_f32_16x16x32_bf16(afr[tr], bfr[tn], acc[tr][tn], 0, 0, 0);
    }
    barrier_fence();
  }
#pragma unroll
  for (int tr = 0; tr < 4; ++tr) {
#pragma unroll
    for (int tn = 0; tn < 2; ++tn) {
#pragma unroll
      for (int rg = 0; rg < 4; ++rg) {
        int o = (w >> 1) * 64 + tr * 16 + l4 * 4 + rg;
        int c = ct * 64 + (w & 1) * 32 + tn * 16 + l15;
        WM[((size_t)b * OC + o) * CIN + c] = f2bf(acc[tr][tn][rg]);
      }
    }
  }
}

// ---------------- K4: out = WM @ imgT^T + b_out (WM-in-regs, pipelined) ----------------
// grid 512 = (b = bi&7 -> XCD, nt = bi>>3: 64-n tiles). 512 thr, LDS 24K.
__global__ __launch_bounds__(512, 2) void k4_mfma(
    const short* __restrict__ WM, const short* __restrict__ imgT,
    const float* __restrict__ b_out, float* __restrict__ out)
{
  const int bi = blockIdx.x;
  const int b = bi & 7, nt = bi >> 3;
  const int n0 = nt * 64;
  const int tid = threadIdx.x, w = tid >> 6, l = tid & 63;
  const int l15 = l & 15, l4 = l >> 4;

  __shared__ __align__(16) char sm4[24576];
  char* B0 = sm4; char* B1 = sm4 + 8192; char* B2 = sm4 + 16384;

  // WM rows in regs: wave w owns o = w*32 + tr*16 + l15
  bf16x8 wreg[2][4][2];
#pragma unroll
  for (int tr = 0; tr < 2; ++tr) {
    int o = w * 32 + tr * 16 + l15;
    const char* base = (const char*)WM + ((size_t)b * OC + o) * 512;
#pragma unroll
    for (int kq = 0; kq < 4; ++kq)
#pragma unroll
      for (int kk = 0; kk < 2; ++kk)
        wreg[tr][kq][kk] = *(const bf16x8*)(base + kq * 128 + kk * 64 + l4 * 16);
  }
  VMCNT(0);

  const char* ibase = (const char*)imgT + ((size_t)b * NSP + n0) * 512;
  const int rowpart = w * 8 + (l >> 3);
  const int colswz = ((l & 7) * 16) ^ (((l >> 3) & 7) << 4);

  auto issue_x = [&](char* buf, int q) {
    const char* src = ibase + (size_t)rowpart * 512 + q * 128 + colswz;
    gl16(src, buf + (size_t)(w * 8) * 128);
  };

  f32x4 acc[2][4];
#pragma unroll
  for (int i = 0; i < 2; ++i)
#pragma unroll
    for (int jj = 0; jj < 4; ++jj) acc[i][jj] = (f32x4){0.f, 0.f, 0.f, 0.f};

#define K4Q(BUF, Q)                                                       \
  {                                                                       \
    _Pragma("unroll")                                                     \
    for (int kk = 0; kk < 2; ++kk) {                                      \
      bf16x8 bfr[4];                                                      \
      _Pragma("unroll")                                                   \
      for (int tn = 0; tn < 4; ++tn) {                                    \
        int n = tn * 16 + l15;                                            \
        bfr[tn] = *(bf16x8*)((BUF) + (size_t)n * 128 +                    \
                  ((kk * 64 + l4 * 16) ^ ((n & 7) << 4)));                \
      }                                                                   \
      __builtin_amdgcn_s_setprio(1);                                      \
      _Pragma("unroll")                                                   \
      for (int tr = 0; tr < 2; ++tr)                                      \
        _Pragma("unroll")                                                 \
        for (int tn = 0; tn < 4; ++tn)                                    \
          acc[tr][tn] = __builtin_amdgcn_mfma_f32_16x16x32_bf16(          \
              wreg[tr][Q][kk], bfr[tn], acc[tr][tn], 0, 0, 0);            \
      __builtin_amdgcn_s_setprio(0);                                      \
    }                                                                     \
  }

  issue_x(B0, 0);
  issue_x(B1, 1);

  VMCNT(1); barrier_fence();
  issue_x(B2, 2);
  K4Q(B0, 0);

  VMCNT(1); barrier_fence();
  issue_x(B0, 3);
  K4Q(B1, 1);

  VMCNT(1); barrier_fence();
  K4Q(B2, 2);

  VMCNT(0); barrier_fence();
  K4Q(B0, 3);

#pragma unroll
  for (int tr = 0; tr < 2; ++tr) {
#pragma unroll
    for (int rg = 0; rg < 4; ++rg) {
      int o = w * 32 + tr * 16 + l4 * 4 + rg;
      float bo = b_out[o];
#pragma unroll
      for (int tn = 0; tn < 4; ++tn) {
        int n = n0 + tn * 16 + l15;
        out[((size_t)b * OC + o) * NSP + n] = acc[tr][tn][rg] + bo;
      }
    }
  }
}

extern "C" void kernel_launch(void* const* d_in, const int* in_sizes, int n_in,
                              void* d_out, int out_size, void* d_ws, size_t ws_size,
                              hipStream_t stream) {
  (void)in_sizes; (void)n_in; (void)out_size; (void)ws_size;
  const float* img   = (const float*)d_in[0];
  const float* w_qkv = (const float*)d_in[1];
  const float* w_out = (const float*)d_in[2];
  const float* b_out = (const float*)d_in[3];
  float* out = (float*)d_out;

  char* ws = (char*)d_ws;
  short* imgT     = (short*)ws;                   // 16,777,216
  short* wkv      = (short*)(ws + 16777216);      //    524,288
  short* wqT      = (short*)(ws + 17301504);      //    262,144
  float* ctx_part = (float*)(ws + 17563648);      //  8,388,608 (64 bh x 8 ch x 4096)
  float* z_part   = (float*)(ws + 25952256);      //    131,072
  short* Mbuf     = (short*)(ws + 26083328);      //  2,097,152
  short* WMbuf    = (short*)(ws + 28180480);      //  1,048,576 (end ~29.2 MB)

  p_transpose<<<dim3(64, 4, BATCH), 256, 0, stream>>>(img, imgT);
  p_weights<<<dim3(256), 256, 0, stream>>>(w_qkv, wkv);
  p_wqT<<<dim3(8, 4), 256, 0, stream>>>(w_qkv, wqT);
  k1_mfma<<<dim3(512), 256, 0, stream>>>(imgT, wkv, ctx_part, z_part);
  k23_fold<<<dim3(HEADS, BATCH), 256, 0, stream>>>(ctx_part, z_part, w_out, Mbuf);
  k3b_mfma<<<dim3(4, 8), 512, 0, stream>>>(Mbuf, wqT, WMbuf);
  k4_mfma<<<dim3(512), 512, 0, stream>>>(WMbuf, imgT, b_out, out);
}

// Round 6
// 110.277 us; speedup vs baseline: 5.0633x; 1.0589x over previous
//
#include <hip/hip_runtime.h>
#include <math.h>
#include <stdint.h>

// GSA linear attention — bf16 MFMA.
// k1: 4-wave blocks (wave = 64 rows x 64 n), W-in-regs (128 VGPR), 3x16KB rotating
// LDS buffers + 32KB phase2 scratch, counted vmcnt. k23: 256-block parallel fold.
// k3b: double-buffered MFMA fold. k4: WM-in-regs streaming GEMM.

typedef __attribute__((ext_vector_type(8))) short bf16x8;
typedef __attribute__((ext_vector_type(4))) float f32x4;

#define BATCH 8
#define CIN 256
#define NSP 4096
#define HEADS 8
#define DK 64
#define HID 512
#define OC 256
#define NCH 8   // k1 chunks of 512 n
#define NT 4    // 128-n tiles per chunk

#define VMCNT(n) asm volatile("s_waitcnt vmcnt(" #n ")" ::: "memory")
#define LGKM0()  asm volatile("s_waitcnt lgkmcnt(0)" ::: "memory")

__device__ __forceinline__ void barrier_fence() {
  asm volatile("" ::: "memory");
  __builtin_amdgcn_s_barrier();
  asm volatile("" ::: "memory");
}

__device__ __forceinline__ void gl16(const void* g, void* l) {
  __builtin_amdgcn_global_load_lds(
      (const __attribute__((address_space(1))) unsigned int*)g,
      (__attribute__((address_space(3))) unsigned int*)l, 16, 0, 0);
}

__device__ __forceinline__ short f2bf(float f) {
  union { float f; uint32_t u; } x; x.f = f;
  uint32_t r = x.u + 0x7fffu + ((x.u >> 16) & 1u);
  return (short)(r >> 16);
}

// ---------------- PREP (fused): imgT transpose + wkv bf16 + wqT transpose ----------------
__global__ __launch_bounds__(256) void prep(
    const float* __restrict__ img, const float* __restrict__ w_qkv,
    short* __restrict__ imgT, short* __restrict__ wkv, short* __restrict__ wqT)
{
  __shared__ float t[64][65];
  const int bid = blockIdx.x;
  if (bid < 2048) {
    // img [b][c][n] f32 -> imgT [b][n][c] bf16
    const int ntile = bid & 63, ctile = (bid >> 6) & 3, b = bid >> 8;
    const float* src = img + ((size_t)b * CIN + ctile * 64) * NSP + ntile * 64;
#pragma unroll
    for (int k = 0; k < 4; ++k) {
      int i = threadIdx.x + k * 256;
      int c = i >> 4, n4 = (i & 15) * 4;
      float4 v = *(const float4*)&src[(size_t)c * NSP + n4];
      t[c][n4 + 0] = v.x; t[c][n4 + 1] = v.y; t[c][n4 + 2] = v.z; t[c][n4 + 3] = v.w;
    }
    __syncthreads();
    short* dst = imgT + ((size_t)b * NSP + ntile * 64) * CIN + ctile * 64;
#pragma unroll
    for (int k = 0; k < 4; ++k) {
      int j = threadIdx.x + k * 256;
      int n = j >> 4, c4 = (j & 15) * 4;
      short r[4] = {f2bf(t[c4 + 0][n]), f2bf(t[c4 + 1][n]),
                    f2bf(t[c4 + 2][n]), f2bf(t[c4 + 3][n])};
      *(uint2*)&dst[(size_t)n * CIN + c4] = *(uint2*)r;
    }
  } else if (bid < 2304) {
    // w_qkv k,v rows [512..1536) f32 -> bf16 [1024][256]
    int i = (bid - 2048) * 256 + threadIdx.x;
    const float* src = w_qkv + (size_t)HID * CIN;
    float4 v = ((const float4*)src)[i];
    short r[4] = {f2bf(v.x), f2bf(v.y), f2bf(v.z), f2bf(v.w)};
    *(uint2*)(wkv + (size_t)i * 4) = *(uint2*)r;
  } else {
    // q rows [0..512) f32 -> WqT [256 c][512 hd] bf16
    const int idx = bid - 2304;
    const int hdt = idx & 7, ct = idx >> 3;
    for (int i = threadIdx.x; i < 4096; i += 256) {
      int r = i >> 6, cc = i & 63;
      t[r][cc] = w_qkv[(size_t)(hdt * 64 + r) * CIN + ct * 64 + cc];
    }
    __syncthreads();
#pragma unroll
    for (int k = 0; k < 4; ++k) {
      int j = threadIdx.x + k * 256;
      int c = j >> 4, h4 = (j & 15) * 4;
      short r[4] = {f2bf(t[h4 + 0][c]), f2bf(t[h4 + 1][c]),
                    f2bf(t[h4 + 2][c]), f2bf(t[h4 + 3][c])};
      *(uint2*)&wqT[(size_t)(ct * 64 + c) * HID + hdt * 64 + h4] = *(uint2*)r;
    }
  }
}

// ---------------- K1: 4-wave (64r x 64n partition) kv-proj + exp + ctx ----------------
// grid 512 (xcd-grouped: 8 h per XCD share (b,ch) img tile). 256 thr. LDS 80K, 2 blocks/CU.
__global__ __launch_bounds__(256, 2) void k1_mfma(
    const short* __restrict__ imgT, const short* __restrict__ wkv,
    float* __restrict__ ctx_part, float* __restrict__ z_part)
{
  const int bi = blockIdx.x;
  const int x = bi & 7, m = bi >> 3;
  const int h = m & 7, g = (m >> 3) * 8 + x;   // g in [0,64)
  const int b = g >> 3, ch = g & 7;

  const int tid = threadIdx.x, w = tid >> 6, l = tid & 63;
  const int l15 = l & 15, l4 = l >> 4;
  const int rw = w & 1;   // 0: k rows 0..63, 1: v rows 0..63
  const int nw = w >> 1;  // n-half (64 n)

  __shared__ __align__(16) char sm[81920];
  char* scr = sm + 49152;   // ek [64][256B] | v [64][256B]

  // W in regs: wave owns 64 rows x full K=256 (32 bf16x8 = 128 VGPR)
  bf16x8 wreg[4][4][2];
#pragma unroll
  for (int tr = 0; tr < 4; ++tr) {
    int rloc = tr * 16 + l15;
    int gr = (rw == 0 ? h * 64 : 512 + h * 64) + rloc;
    const char* base = (const char*)wkv + (size_t)gr * 512;
#pragma unroll
    for (int kq = 0; kq < 4; ++kq)
#pragma unroll
      for (int kk = 0; kk < 2; ++kk)
        wreg[tr][kq][kk] = *(const bf16x8*)(base + kq * 128 + kk * 64 + l4 * 16);
  }
  VMCNT(0);   // clean vmcnt before gl16 pipeline

  const char* ibase = (const char*)imgT + (size_t)b * NSP * 512 + (size_t)ch * 512 * 512;
  const int rowpart = w * 8 + (l >> 3);
  const int colswz = ((l & 7) * 16) ^ (((l >> 3) & 7) << 4);

  auto issue_x = [&](char* buf, int t, int q) {
#pragma unroll
    for (int r = 0; r < 4; ++r) {
      int row = rowpart + r * 32;
      const char* src = ibase + (size_t)(t * 128 + row) * 512 + q * 128 + colswz;
      gl16(src, buf + (size_t)(w * 8 + r * 32) * 128);
    }
  };

  char* p0 = sm; char* p1 = sm + 16384; char* p2 = sm + 32768;
  issue_x(p0, 0, 0);
  issue_x(p1, 0, 1);

  f32x4 acc2[2][2];
#pragma unroll
  for (int i = 0; i < 2; ++i)
#pragma unroll
    for (int j = 0; j < 2; ++j) acc2[i][j] = (f32x4){0.f, 0.f, 0.f, 0.f};
  float zacc[4][4];
#pragma unroll
  for (int i = 0; i < 4; ++i)
#pragma unroll
    for (int jj = 0; jj < 4; ++jj) zacc[i][jj] = 0.f;

#define P1Q(BUF, Q)                                                       \
  {                                                                       \
    _Pragma("unroll")                                                     \
    for (int kk = 0; kk < 2; ++kk) {                                      \
      bf16x8 bfr[4];                                                      \
      _Pragma("unroll")                                                   \
      for (int tn = 0; tn < 4; ++tn) {                                    \
        int n = nw * 64 + tn * 16 + l15;                                  \
        bfr[tn] = *(bf16x8*)((BUF) + (size_t)n * 128 +                    \
                  ((kk * 64 + l4 * 16) ^ ((n & 7) << 4)));                \
      }                                                                   \
      __builtin_amdgcn_s_setprio(1);                                      \
      _Pragma("unroll")                                                   \
      for (int tr = 0; tr < 4; ++tr)                                      \
        _Pragma("unroll")                                                 \
        for (int tn = 0; tn < 4; ++tn)                                    \
          acc1[tr][tn] = __builtin_amdgcn_mfma_f32_16x16x32_bf16(         \
              wreg[tr][Q][kk], bfr[tn], acc1[tr][tn], 0, 0, 0);           \
      __builtin_amdgcn_s_setprio(0);                                      \
    }                                                                     \
  }

  for (int t = 0; t < NT; ++t) {
    const bool last = (t == NT - 1);
    f32x4 acc1[4][4];
#pragma unroll
    for (int i = 0; i < 4; ++i)
#pragma unroll
      for (int jj = 0; jj < 4; ++jj) acc1[i][jj] = (f32x4){0.f, 0.f, 0.f, 0.f};

    VMCNT(4); barrier_fence();
    issue_x(p2, t, 2);
    P1Q(p0, 0);

    VMCNT(4); barrier_fence();
    issue_x(p0, t, 3);
    P1Q(p1, 1);

    VMCNT(4); barrier_fence();
    if (!last) issue_x(p1, t + 1, 0);
    P1Q(p2, 2);

    if (last) { VMCNT(0); } else { VMCNT(4); }
    barrier_fence();
    if (!last) issue_x(p2, t + 1, 1);
    P1Q(p0, 3);

    // ---- phase2 pack: k-waves -> exp rows 0..63 (their n-half), v-waves -> v rows ----
    {
      char* dst = (rw == 0) ? scr : (scr + 16384);
#pragma unroll
      for (int tr = 0; tr < 4; ++tr) {
#pragma unroll
        for (int tn = 0; tn < 4; ++tn) {
          unsigned short us[4];
          f32x4 vv = acc1[tr][tn];
#pragma unroll
          for (int rg = 0; rg < 4; ++rg) {
            float f = vv[rg];
            if (rw == 0) { f = __expf(f); zacc[tr][rg] += f; }
            us[rg] = (unsigned short)f2bf(f);
          }
          unsigned p01 = us[0] | ((unsigned)us[1] << 16);
          unsigned p23 = us[2] | ((unsigned)us[3] << 16);
          unsigned q01 = (unsigned)__shfl_xor((int)p01, 1, 64);
          unsigned q23 = (unsigned)__shfl_xor((int)p23, 1, 64);
          int nl = nw * 64 + tn * 16 + l15;
          int nb = 2 * (nl & ~1);
          int r0 = tr * 16 + l4 * 4;
          unsigned w0, w1; int rga, rgb;
          if (!(l15 & 1)) {
            w0 = (p01 & 0xffffu) | (q01 << 16);
            w1 = (p01 >> 16) | (q01 & 0xffff0000u);
            rga = 0; rgb = 1;
          } else {
            w0 = (q23 & 0xffffu) | (p23 << 16);
            w1 = (q23 >> 16) | (p23 & 0xffff0000u);
            rga = 2; rgb = 3;
          }
          int rowa = r0 + rga, rowbq = r0 + rgb;
          *(unsigned*)(dst + (size_t)rowa * 256 + (nb ^ ((rowa & 7) << 4))) = w0;
          *(unsigned*)(dst + (size_t)rowbq * 256 + (nb ^ ((rowbq & 7) << 4))) = w1;
        }
      }
    }
    LGKM0(); barrier_fence();
    // ---- ctx MFMA 2x2: wave (rw,nw) -> d-quadrant rw*32, e-quadrant nw*32, K=128 ----
#pragma unroll
    for (int kk = 0; kk < 4; ++kk) {
      int d0 = rw * 32 + l15, e0 = nw * 32 + l15;
      bf16x8 a0 = *(bf16x8*)(scr + (size_t)d0 * 256 +
                             ((kk * 64 + l4 * 16) ^ ((d0 & 7) << 4)));
      bf16x8 a1 = *(bf16x8*)(scr + (size_t)(d0 + 16) * 256 +
                             ((kk * 64 + l4 * 16) ^ (((d0 + 16) & 7) << 4)));
      bf16x8 b0 = *(bf16x8*)(scr + 16384 + (size_t)e0 * 256 +
                             ((kk * 64 + l4 * 16) ^ ((e0 & 7) << 4)));
      bf16x8 b1 = *(bf16x8*)(scr + 16384 + (size_t)(e0 + 16) * 256 +
                             ((kk * 64 + l4 * 16) ^ (((e0 + 16) & 7) << 4)));
      __builtin_amdgcn_s_setprio(1);
      acc2[0][0] = __builtin_amdgcn_mfma_f32_16x16x32_bf16(a0, b0, acc2[0][0], 0, 0, 0);
      acc2[0][1] = __builtin_amdgcn_mfma_f32_16x16x32_bf16(a0, b1, acc2[0][1], 0, 0, 0);
      acc2[1][0] = __builtin_amdgcn_mfma_f32_16x16x32_bf16(a1, b0, acc2[1][0], 0, 0, 0);
      acc2[1][1] = __builtin_amdgcn_mfma_f32_16x16x32_bf16(a1, b1, acc2[1][1], 0, 0, 0);
      __builtin_amdgcn_s_setprio(0);
    }
    // scratch reused only after 4 more barriers next t
    { char* tmp = p0; p0 = p1; p1 = p2; p2 = tmp; }
  }

  // ---- epilogue: ctx quadrant + z ----
  float* cp = ctx_part + ((size_t)(b * HEADS + h) * NCH + ch) * (DK * DK);
#pragma unroll
  for (int i = 0; i < 2; ++i)
#pragma unroll
    for (int j = 0; j < 2; ++j)
#pragma unroll
      for (int rg = 0; rg < 4; ++rg) {
        int d = rw * 32 + i * 16 + l4 * 4 + rg;
        int e = nw * 32 + j * 16 + l15;
        cp[d * 64 + e] = acc2[i][j][rg];
      }
  __syncthreads();
  float* zl = (float*)sm;
  if (rw == 0) {
#pragma unroll
    for (int tr = 0; tr < 4; ++tr) {
#pragma unroll
      for (int rg = 0; rg < 4; ++rg) {
        float z = zacc[tr][rg];
        z += __shfl_xor(z, 1, 64); z += __shfl_xor(z, 2, 64);
        z += __shfl_xor(z, 4, 64); z += __shfl_xor(z, 8, 64);
        if (l15 == 0) zl[nw * 64 + tr * 16 + l4 * 4 + rg] = z;
      }
    }
  }
  __syncthreads();
  if (tid < 64)
    z_part[((size_t)(b * HEADS + h) * NCH + ch) * DK + tid] = zl[tid] + zl[64 + tid];
}

// ---------------- K23: reduce+normalize ctx, fold w_out -> M (bf16). grid 256 ----------------
__global__ __launch_bounds__(256) void k23_fold(
    const float* __restrict__ ctx_part, const float* __restrict__ z_part,
    const float* __restrict__ w_out, short* __restrict__ M)
{
  const int bid = blockIdx.x;
  const int h = bid & 7, b = (bid >> 3) & 7, ds = bid >> 6;  // ds: 4 groups of 16 d
  const int bh = b * HEADS + h;
  const int d0 = ds * 16;
  __shared__ float cs[16][64];
  __shared__ float zs[16];

  {
    const int idx = threadIdx.x;
    const int dd = idx >> 4, e4 = (idx & 15) * 4;
    float4 s = {0.f, 0.f, 0.f, 0.f};
    for (int chh = 0; chh < NCH; ++chh) {
      const float* p = ctx_part + ((size_t)bh * NCH + chh) * 4096 + (d0 + dd) * 64 + e4;
      float4 v = *(const float4*)p;
      s.x += v.x; s.y += v.y; s.z += v.z; s.w += v.w;
    }
    if ((idx & 15) == 0) {
      float z = 0.f;
      for (int chh = 0; chh < NCH; ++chh)
        z += z_part[((size_t)bh * NCH + chh) * DK + d0 + dd];
      zs[dd] = z;
    }
    cs[dd][e4 + 0] = s.x; cs[dd][e4 + 1] = s.y;
    cs[dd][e4 + 2] = s.z; cs[dd][e4 + 3] = s.w;
  }
  __syncthreads();
  {
    const int idx = threadIdx.x;
    const int dd = idx >> 4, e4 = (idx & 15) * 4;
    float inv = 1.f / zs[dd];
    cs[dd][e4 + 0] *= inv; cs[dd][e4 + 1] *= inv;
    cs[dd][e4 + 2] *= inv; cs[dd][e4 + 3] *= inv;
  }
  __syncthreads();
  const int o = threadIdx.x;
  float4 wr[16];
#pragma unroll
  for (int q = 0; q < 16; ++q)
    wr[q] = *(const float4*)&w_out[(size_t)o * HID + h * DK + q * 4];
#pragma unroll
  for (int dd = 0; dd < 16; ++dd) {
    float a = 0.f;
#pragma unroll
    for (int q = 0; q < 16; ++q) {
      float4 w4 = wr[q];
      a += w4.x * cs[dd][q * 4 + 0] + w4.y * cs[dd][q * 4 + 1]
         + w4.z * cs[dd][q * 4 + 2] + w4.w * cs[dd][q * 4 + 3];
    }
    M[((size_t)b * OC + o) * HID + h * DK + d0 + dd] = f2bf(a);
  }
}

// ---------------- K3b: WM[b,o,c] = M[b,o,:] @ WqT[c,:]  (MFMA, double-buffered) ----------------
__global__ __launch_bounds__(512) void k3b_mfma(
    const short* __restrict__ M, const short* __restrict__ wqT,
    short* __restrict__ WM)
{
  const int ct = blockIdx.x, b = blockIdx.y;
  const int tid = threadIdx.x, w = tid >> 6, l = tid & 63;
  const int l15 = l & 15, l4 = l >> 4;

  __shared__ __align__(16) char sm3[81920];   // 2 x (At 32K + Bt 8K)

  f32x4 acc[4][2];
#pragma unroll
  for (int i = 0; i < 4; ++i)
#pragma unroll
    for (int jj = 0; jj < 2; ++jj) acc[i][jj] = (f32x4){0.f, 0.f, 0.f, 0.f};

  const int srow = tid >> 3, scol = (tid & 7) * 16;
  auto issue = [&](int st, int pb) {
    char* Ab = sm3 + pb * 40960;
    char* Bb = sm3 + 32768 + pb * 40960;
#pragma unroll
    for (int p = 0; p < 4; ++p) {
      int row = p * 64 + srow;
      const char* src = (const char*)M + ((size_t)b * OC + row) * 1024 + st * 128
                        + (scol ^ ((row & 7) << 4));
      gl16(src, Ab + (size_t)(p * 64 + w * 8) * 128);
    }
    {
      int row = srow;
      const char* src = (const char*)wqT + (size_t)(ct * 64 + row) * 1024 + st * 128
                        + (scol ^ ((row & 7) << 4));
      gl16(src, Bb + (size_t)(w * 8) * 128);
    }
  };

  issue(0, 0);
  for (int st = 0; st < 8; ++st) {
    const int pb = st & 1;
    if (st < 7) { issue(st + 1, pb ^ 1); VMCNT(5); } else { VMCNT(0); }
    barrier_fence();
    char* At = sm3 + pb * 40960;
    char* Bt = sm3 + 32768 + pb * 40960;
#pragma unroll
    for (int kk = 0; kk < 2; ++kk) {
      bf16x8 afr[4], bfr[2];
#pragma unroll
      for (int tr = 0; tr < 4; ++tr) {
        int o = (w >> 1) * 64 + tr * 16 + l15;
        afr[tr] = *(bf16x8*)(At + (size_t)o * 128 + ((kk * 64 + l4 * 16) ^ ((o & 7) << 4)));
      }
#pragma unroll
      for (int tn = 0; tn < 2; ++tn) {
        int c = (w & 1) * 32 + tn * 16 + l15;
        bfr[tn] = *(bf16x8*)(Bt + (size_t)c * 128 + ((kk * 64 + l4 * 16) ^ ((c & 7) << 4)));
      }
#pragma unroll
      for (int tr = 0; tr < 4; ++tr)
#pragma unroll
        for (int tn = 0; tn < 2; ++tn)
          acc[tr][tn] = __builtin_amdgcn_mfma_f32_16x16x32_bf16(afr[tr], bfr[tn], acc[tr][tn], 0, 0, 0);
    }
    barrier_fence();
  }
#pragma unroll
  for (int tr = 0; tr < 4; ++tr) {
#pragma unroll
    for (int tn = 0; tn < 2; ++tn) {
#pragma unroll
      for (int rg = 0; rg < 4; ++rg) {
        int o = (w >> 1) * 64 + tr * 16 + l4 * 4 + rg;
        int c = ct * 64 + (w & 1) * 32 + tn * 16 + l15;
        WM[((size_t)b * OC + o) * CIN + c] = f2bf(acc[tr][tn][rg]);
      }
    }
  }
}

// ---------------- K4: out = WM @ imgT^T + b_out (WM-in-regs, pipelined) ----------------
__global__ __launch_bounds__(512, 2) void k4_mfma(
    const short* __restrict__ WM, const short* __restrict__ imgT,
    const float* __restrict__ b_out, float* __restrict__ out)
{
  const int bi = blockIdx.x;
  const int b = bi & 7, nt = bi >> 3;
  const int n0 = nt * 64;
  const int tid = threadIdx.x, w = tid >> 6, l = tid & 63;
  const int l15 = l & 15, l4 = l >> 4;

  __shared__ __align__(16) char sm4[24576];
  char* B0 = sm4; char* B1 = sm4 + 8192; char* B2 = sm4 + 16384;

  bf16x8 wreg[2][4][2];
#pragma unroll
  for (int tr = 0; tr < 2; ++tr) {
    int o = w * 32 + tr * 16 + l15;
    const char* base = (const char*)WM + ((size_t)b * OC + o) * 512;
#pragma unroll
    for (int kq = 0; kq < 4; ++kq)
#pragma unroll
      for (int kk = 0; kk < 2; ++kk)
        wreg[tr][kq][kk] = *(const bf16x8*)(base + kq * 128 + kk * 64 + l4 * 16);
  }
  VMCNT(0);

  const char* ibase = (const char*)imgT + ((size_t)b * NSP + n0) * 512;
  const int rowpart = w * 8 + (l >> 3);
  const int colswz = ((l & 7) * 16) ^ (((l >> 3) & 7) << 4);

  auto issue_x = [&](char* buf, int q) {
    const char* src = ibase + (size_t)rowpart * 512 + q * 128 + colswz;
    gl16(src, buf + (size_t)(w * 8) * 128);
  };

  f32x4 acc[2][4];
#pragma unroll
  for (int i = 0; i < 2; ++i)
#pragma unroll
    for (int jj = 0; jj < 4; ++jj) acc[i][jj] = (f32x4){0.f, 0.f, 0.f, 0.f};

#define K4Q(BUF, Q)                                                       \
  {                                                                       \
    _Pragma("unroll")                                                     \
    for (int kk = 0; kk < 2; ++kk) {                                      \
      bf16x8 bfr[4];                                                      \
      _Pragma("unroll")                                                   \
      for (int tn = 0; tn < 4; ++tn) {                                    \
        int n = tn * 16 + l15;                                            \
        bfr[tn] = *(bf16x8*)((BUF) + (size_t)n * 128 +                    \
                  ((kk * 64 + l4 * 16) ^ ((n & 7) << 4)));                \
      }                                                                   \
      __builtin_amdgcn_s_setprio(1);                                      \
      _Pragma("unroll")                                                   \
      for (int tr = 0; tr < 2; ++tr)                                      \
        _Pragma("unroll")                                                 \
        for (int tn = 0; tn < 4; ++tn)                                    \
          acc[tr][tn] = __builtin_amdgcn_mfma_f32_16x16x32_bf16(          \
              wreg[tr][Q][kk], bfr[tn], acc[tr][tn], 0, 0, 0);            \
      __builtin_amdgcn_s_setprio(0);                                      \
    }                                                                     \
  }

  issue_x(B0, 0);
  issue_x(B1, 1);

  VMCNT(1); barrier_fence();
  issue_x(B2, 2);
  K4Q(B0, 0);

  VMCNT(1); barrier_fence();
  issue_x(B0, 3);
  K4Q(B1, 1);

  VMCNT(1); barrier_fence();
  K4Q(B2, 2);

  VMCNT(0); barrier_fence();
  K4Q(B0, 3);

#pragma unroll
  for (int tr = 0; tr < 2; ++tr) {
#pragma unroll
    for (int rg = 0; rg < 4; ++rg) {
      int o = w * 32 + tr * 16 + l4 * 4 + rg;
      float bo = b_out[o];
#pragma unroll
      for (int tn = 0; tn < 4; ++tn) {
        int n = n0 + tn * 16 + l15;
        out[((size_t)b * OC + o) * NSP + n] = acc[tr][tn][rg] + bo;
      }
    }
  }
}

extern "C" void kernel_launch(void* const* d_in, const int* in_sizes, int n_in,
                              void* d_out, int out_size, void* d_ws, size_t ws_size,
                              hipStream_t stream) {
  (void)in_sizes; (void)n_in; (void)out_size; (void)ws_size;
  const float* img   = (const float*)d_in[0];
  const float* w_qkv = (const float*)d_in[1];
  const float* w_out = (const float*)d_in[2];
  const float* b_out = (const float*)d_in[3];
  float* out = (float*)d_out;

  char* ws = (char*)d_ws;
  short* imgT     = (short*)ws;                   // 16,777,216
  short* wkv      = (short*)(ws + 16777216);      //    524,288
  short* wqT      = (short*)(ws + 17301504);      //    262,144
  float* ctx_part = (float*)(ws + 17563648);      //  8,388,608 (64 bh x 8 ch x 4096)
  float* z_part   = (float*)(ws + 25952256);      //    131,072
  short* Mbuf     = (short*)(ws + 26083328);      //  2,097,152
  short* WMbuf    = (short*)(ws + 28180480);      //  1,048,576 (end ~29.2 MB)

  prep<<<dim3(2336), 256, 0, stream>>>(img, w_qkv, imgT, wkv, wqT);
  k1_mfma<<<dim3(512), 256, 0, stream>>>(imgT, wkv, ctx_part, z_part);
  k23_fold<<<dim3(256), 256, 0, stream>>>(ctx_part, z_part, w_out, Mbuf);
  k3b_mfma<<<dim3(4, 8), 512, 0, stream>>>(Mbuf, wqT, WMbuf);
  k4_mfma<<<dim3(512), 512, 0, stream>>>(WMbuf, imgT, b_out, out);
}

// Round 7
// 82.519 us; speedup vs baseline: 6.7665x; 1.3364x over previous
//
#include <hip/hip_runtime.h>
#include <math.h>
#include <stdint.h>

// GSA linear attention — bf16 MFMA.
// k1: R5 partition (wave = 32 rows x 128 n, W-in-regs 64 VGPR, 3x16KB rotating
// buffers + 32KB phase2 scratch, counted vmcnt) + cvt_pk_bf16 pack.
// prep fused; k23 256-block; k3b double-buffered MFMA; k4 WM-in-regs streaming.

typedef __attribute__((ext_vector_type(8))) short bf16x8;
typedef __attribute__((ext_vector_type(4))) float f32x4;

#define BATCH 8
#define CIN 256
#define NSP 4096
#define HEADS 8
#define DK 64
#define HID 512
#define OC 256
#define NCH 8   // k1 chunks of 512 n
#define NT 4    // 128-n tiles per chunk

#define VMCNT(n) asm volatile("s_waitcnt vmcnt(" #n ")" ::: "memory")
#define LGKM0()  asm volatile("s_waitcnt lgkmcnt(0)" ::: "memory")

__device__ __forceinline__ void barrier_fence() {
  asm volatile("" ::: "memory");
  __builtin_amdgcn_s_barrier();
  asm volatile("" ::: "memory");
}

__device__ __forceinline__ void gl16(const void* g, void* l) {
  __builtin_amdgcn_global_load_lds(
      (const __attribute__((address_space(1))) unsigned int*)g,
      (__attribute__((address_space(3))) unsigned int*)l, 16, 0, 0);
}

__device__ __forceinline__ short f2bf(float f) {
  union { float f; uint32_t u; } x; x.f = f;
  uint32_t r = x.u + 0x7fffu + ((x.u >> 16) & 1u);
  return (short)(r >> 16);
}

__device__ __forceinline__ unsigned cvt_pk_bf16(float lo, float hi) {
  unsigned r;
  asm("v_cvt_pk_bf16_f32 %0, %1, %2" : "=v"(r) : "v"(lo), "v"(hi));
  return r;
}

// ---------------- PREP (fused): imgT transpose + wkv bf16 + wqT transpose ----------------
__global__ __launch_bounds__(256) void prep(
    const float* __restrict__ img, const float* __restrict__ w_qkv,
    short* __restrict__ imgT, short* __restrict__ wkv, short* __restrict__ wqT)
{
  __shared__ float t[64][65];
  const int bid = blockIdx.x;
  if (bid < 2048) {
    const int ntile = bid & 63, ctile = (bid >> 6) & 3, b = bid >> 8;
    const float* src = img + ((size_t)b * CIN + ctile * 64) * NSP + ntile * 64;
#pragma unroll
    for (int k = 0; k < 4; ++k) {
      int i = threadIdx.x + k * 256;
      int c = i >> 4, n4 = (i & 15) * 4;
      float4 v = *(const float4*)&src[(size_t)c * NSP + n4];
      t[c][n4 + 0] = v.x; t[c][n4 + 1] = v.y; t[c][n4 + 2] = v.z; t[c][n4 + 3] = v.w;
    }
    __syncthreads();
    short* dst = imgT + ((size_t)b * NSP + ntile * 64) * CIN + ctile * 64;
#pragma unroll
    for (int k = 0; k < 4; ++k) {
      int j = threadIdx.x + k * 256;
      int n = j >> 4, c4 = (j & 15) * 4;
      short r[4] = {f2bf(t[c4 + 0][n]), f2bf(t[c4 + 1][n]),
                    f2bf(t[c4 + 2][n]), f2bf(t[c4 + 3][n])};
      *(uint2*)&dst[(size_t)n * CIN + c4] = *(uint2*)r;
    }
  } else if (bid < 2304) {
    int i = (bid - 2048) * 256 + threadIdx.x;
    const float* src = w_qkv + (size_t)HID * CIN;
    float4 v = ((const float4*)src)[i];
    short r[4] = {f2bf(v.x), f2bf(v.y), f2bf(v.z), f2bf(v.w)};
    *(uint2*)(wkv + (size_t)i * 4) = *(uint2*)r;
  } else {
    const int idx = bid - 2304;
    const int hdt = idx & 7, ct = idx >> 3;
    for (int i = threadIdx.x; i < 4096; i += 256) {
      int r = i >> 6, cc = i & 63;
      t[r][cc] = w_qkv[(size_t)(hdt * 64 + r) * CIN + ct * 64 + cc];
    }
    __syncthreads();
#pragma unroll
    for (int k = 0; k < 4; ++k) {
      int j = threadIdx.x + k * 256;
      int c = j >> 4, h4 = (j & 15) * 4;
      short r[4] = {f2bf(t[h4 + 0][c]), f2bf(t[h4 + 1][c]),
                    f2bf(t[h4 + 2][c]), f2bf(t[h4 + 3][c])};
      *(uint2*)&wqT[(size_t)(ct * 64 + c) * HID + hdt * 64 + h4] = *(uint2*)r;
    }
  }
}

// ---------------- K1: 4-wave pipelined kv-proj + exp + ctx (R5 partition) ----------------
// grid 512 (xcd-grouped: 8 h per XCD share (b,ch)). 256 thr. LDS 80K -> 2 blocks/CU.
__global__ __launch_bounds__(256, 2) void k1_mfma(
    const short* __restrict__ imgT, const short* __restrict__ wkv,
    float* __restrict__ ctx_part, float* __restrict__ z_part)
{
  const int bi = blockIdx.x;
  const int x = bi & 7, m = bi >> 3;
  const int h = m & 7, g = (m >> 3) * 8 + x;   // g in [0,64)
  const int b = g >> 3, ch = g & 7;

  const int tid = threadIdx.x, w = tid >> 6, l = tid & 63;
  const int l15 = l & 15, l4 = l >> 4;

  __shared__ __align__(16) char sm[81920];
  char* scr = sm + 49152;   // ek [64][256B] | v [64][256B]

  // W in regs: wave w owns rows w*32..w*32+31 (w<2: k, w>=2: v)
  bf16x8 wreg[2][4][2];
#pragma unroll
  for (int tr = 0; tr < 2; ++tr) {
    int row = w * 32 + tr * 16 + l15;
    int gr = (row < 64) ? (h * 64 + row) : (512 + h * 64 + (row - 64));
    const char* base = (const char*)wkv + (size_t)gr * 512;
#pragma unroll
    for (int kq = 0; kq < 4; ++kq)
#pragma unroll
      for (int kk = 0; kk < 2; ++kk)
        wreg[tr][kq][kk] = *(const bf16x8*)(base + kq * 128 + kk * 64 + l4 * 16);
  }
  VMCNT(0);   // clean vmcnt before gl16 pipeline

  const char* ibase = (const char*)imgT + (size_t)b * NSP * 512 + (size_t)ch * 512 * 512;
  const int rowpart = w * 8 + (l >> 3);
  const int colswz = ((l & 7) * 16) ^ (((l >> 3) & 7) << 4);

  auto issue_x = [&](char* buf, int t, int q) {
#pragma unroll
    for (int r = 0; r < 4; ++r) {
      int row = rowpart + r * 32;
      const char* src = ibase + (size_t)(t * 128 + row) * 512 + q * 128 + colswz;
      gl16(src, buf + (size_t)(w * 8 + r * 32) * 128);
    }
  };

  char* p0 = sm; char* p1 = sm + 16384; char* p2 = sm + 32768;
  issue_x(p0, 0, 0);
  issue_x(p1, 0, 1);

  f32x4 acc2[4];
#pragma unroll
  for (int i = 0; i < 4; ++i) acc2[i] = (f32x4){0.f, 0.f, 0.f, 0.f};
  float zacc[2][4];
#pragma unroll
  for (int i = 0; i < 2; ++i)
#pragma unroll
    for (int jj = 0; jj < 4; ++jj) zacc[i][jj] = 0.f;

#define P1Q(BUF, Q)                                                       \
  {                                                                       \
    _Pragma("unroll")                                                     \
    for (int kk = 0; kk < 2; ++kk) {                                      \
      bf16x8 bfr[8];                                                      \
      _Pragma("unroll")                                                   \
      for (int tn = 0; tn < 8; ++tn) {                                    \
        int n = tn * 16 + l15;                                            \
        bfr[tn] = *(bf16x8*)((BUF) + (size_t)n * 128 +                    \
                  ((kk * 64 + l4 * 16) ^ ((n & 7) << 4)));                \
      }                                                                   \
      __builtin_amdgcn_s_setprio(1);                                      \
      _Pragma("unroll")                                                   \
      for (int tr = 0; tr < 2; ++tr)                                      \
        _Pragma("unroll")                                                 \
        for (int tn = 0; tn < 8; ++tn)                                    \
          acc1[tr][tn] = __builtin_amdgcn_mfma_f32_16x16x32_bf16(         \
              wreg[tr][Q][kk], bfr[tn], acc1[tr][tn], 0, 0, 0);           \
      __builtin_amdgcn_s_setprio(0);                                      \
    }                                                                     \
  }

  for (int t = 0; t < NT; ++t) {
    const bool last = (t == NT - 1);
    f32x4 acc1[2][8];
#pragma unroll
    for (int i = 0; i < 2; ++i)
#pragma unroll
      for (int jj = 0; jj < 8; ++jj) acc1[i][jj] = (f32x4){0.f, 0.f, 0.f, 0.f};

    VMCNT(4); barrier_fence();
    issue_x(p2, t, 2);
    P1Q(p0, 0);

    VMCNT(4); barrier_fence();
    issue_x(p0, t, 3);
    P1Q(p1, 1);

    VMCNT(4); barrier_fence();
    if (!last) issue_x(p1, t + 1, 0);
    P1Q(p2, 2);

    if (last) { VMCNT(0); } else { VMCNT(4); }
    barrier_fence();
    if (!last) issue_x(p2, t + 1, 1);
    P1Q(p0, 3);

    // ---- phase2 pack (cvt_pk): all 4 waves write their 32 rows to scratch ----
    {
      char* dst = (w < 2) ? scr : (scr + 16384);
      const int rowb = (w & 1) * 32;
#pragma unroll
      for (int tr = 0; tr < 2; ++tr) {
#pragma unroll
        for (int tn = 0; tn < 8; ++tn) {
          f32x4 vv = acc1[tr][tn];
          float f0 = vv[0], f1 = vv[1], f2 = vv[2], f3 = vv[3];
          if (w < 2) {
            f0 = __expf(f0); f1 = __expf(f1); f2 = __expf(f2); f3 = __expf(f3);
            zacc[tr][0] += f0; zacc[tr][1] += f1;
            zacc[tr][2] += f2; zacc[tr][3] += f3;
          }
          unsigned p01 = cvt_pk_bf16(f0, f1);   // rows r0, r0+1 (same n)
          unsigned p23 = cvt_pk_bf16(f2, f3);   // rows r0+2, r0+3
          unsigned q01 = (unsigned)__shfl_xor((int)p01, 1, 64);
          unsigned q23 = (unsigned)__shfl_xor((int)p23, 1, 64);
          int nl = tn * 16 + l15;
          int nb = 2 * (nl & ~1);
          int r0 = rowb + tr * 16 + l4 * 4;
          unsigned w0, w1; int rga, rgb;
          if (!(l15 & 1)) {   // even lane writes rows r0, r0+1 as (n,n+1) pairs
            w0 = (p01 & 0xffffu) | (q01 << 16);
            w1 = (p01 >> 16) | (q01 & 0xffff0000u);
            rga = 0; rgb = 1;
          } else {            // odd lane writes rows r0+2, r0+3
            w0 = (q23 & 0xffffu) | (p23 << 16);
            w1 = (q23 >> 16) | (p23 & 0xffff0000u);
            rga = 2; rgb = 3;
          }
          int rowa = r0 + rga, rowbq = r0 + rgb;
          *(unsigned*)(dst + (size_t)rowa * 256 + (nb ^ ((rowa & 7) << 4))) = w0;
          *(unsigned*)(dst + (size_t)rowbq * 256 + (nb ^ ((rowbq & 7) << 4))) = w1;
        }
      }
    }
    LGKM0(); barrier_fence();
    // ---- ctx MFMA: wave w = d-tile (16 d) x 4 e-tiles, K = 128 n ----
#pragma unroll
    for (int kk = 0; kk < 4; ++kk) {
      int dr = w * 16 + l15;
      bf16x8 a = *(bf16x8*)(scr + (size_t)dr * 256 + ((kk * 64 + l4 * 16) ^ ((dr & 7) << 4)));
      __builtin_amdgcn_s_setprio(1);
#pragma unroll
      for (int te = 0; te < 4; ++te) {
        int er = te * 16 + l15;
        bf16x8 bv = *(bf16x8*)(scr + 16384 + (size_t)er * 256 +
                               ((kk * 64 + l4 * 16) ^ ((er & 7) << 4)));
        acc2[te] = __builtin_amdgcn_mfma_f32_16x16x32_bf16(a, bv, acc2[te], 0, 0, 0);
      }
      __builtin_amdgcn_s_setprio(0);
    }
    // scratch reused only after 4 more barriers next t
    { char* tmp = p0; p0 = p1; p1 = p2; p2 = tmp; }
  }

  // ---- epilogue ----
  float* cp = ctx_part + ((size_t)(b * HEADS + h) * NCH + ch) * (DK * DK);
#pragma unroll
  for (int te = 0; te < 4; ++te) {
#pragma unroll
    for (int rg = 0; rg < 4; ++rg) {
      int d = w * 16 + l4 * 4 + rg;
      int e = te * 16 + l15;
      cp[d * 64 + e] = acc2[te][rg];
    }
  }
  if (w < 2) {
#pragma unroll
    for (int tr = 0; tr < 2; ++tr) {
#pragma unroll
      for (int rg = 0; rg < 4; ++rg) {
        float z = zacc[tr][rg];
        z += __shfl_xor(z, 1, 64); z += __shfl_xor(z, 2, 64);
        z += __shfl_xor(z, 4, 64); z += __shfl_xor(z, 8, 64);
        if (l15 == 0) {
          int d = w * 32 + tr * 16 + l4 * 4 + rg;
          z_part[((size_t)(b * HEADS + h) * NCH + ch) * DK + d] = z;
        }
      }
    }
  }
}

// ---------------- K23: reduce+normalize ctx, fold w_out -> M (bf16). grid 256 ----------------
__global__ __launch_bounds__(256) void k23_fold(
    const float* __restrict__ ctx_part, const float* __restrict__ z_part,
    const float* __restrict__ w_out, short* __restrict__ M)
{
  const int bid = blockIdx.x;
  const int h = bid & 7, b = (bid >> 3) & 7, ds = bid >> 6;
  const int bh = b * HEADS + h;
  const int d0 = ds * 16;
  __shared__ float cs[16][64];
  __shared__ float zs[16];

  {
    const int idx = threadIdx.x;
    const int dd = idx >> 4, e4 = (idx & 15) * 4;
    float4 s = {0.f, 0.f, 0.f, 0.f};
    for (int chh = 0; chh < NCH; ++chh) {
      const float* p = ctx_part + ((size_t)bh * NCH + chh) * 4096 + (d0 + dd) * 64 + e4;
      float4 v = *(const float4*)p;
      s.x += v.x; s.y += v.y; s.z += v.z; s.w += v.w;
    }
    if ((idx & 15) == 0) {
      float z = 0.f;
      for (int chh = 0; chh < NCH; ++chh)
        z += z_part[((size_t)bh * NCH + chh) * DK + d0 + dd];
      zs[dd] = z;
    }
    cs[dd][e4 + 0] = s.x; cs[dd][e4 + 1] = s.y;
    cs[dd][e4 + 2] = s.z; cs[dd][e4 + 3] = s.w;
  }
  __syncthreads();
  {
    const int idx = threadIdx.x;
    const int dd = idx >> 4, e4 = (idx & 15) * 4;
    float inv = 1.f / zs[dd];
    cs[dd][e4 + 0] *= inv; cs[dd][e4 + 1] *= inv;
    cs[dd][e4 + 2] *= inv; cs[dd][e4 + 3] *= inv;
  }
  __syncthreads();
  const int o = threadIdx.x;
  float4 wr[16];
#pragma unroll
  for (int q = 0; q < 16; ++q)
    wr[q] = *(const float4*)&w_out[(size_t)o * HID + h * DK + q * 4];
#pragma unroll
  for (int dd = 0; dd < 16; ++dd) {
    float a = 0.f;
#pragma unroll
    for (int q = 0; q < 16; ++q) {
      float4 w4 = wr[q];
      a += w4.x * cs[dd][q * 4 + 0] + w4.y * cs[dd][q * 4 + 1]
         + w4.z * cs[dd][q * 4 + 2] + w4.w * cs[dd][q * 4 + 3];
    }
    M[((size_t)b * OC + o) * HID + h * DK + d0 + dd] = f2bf(a);
  }
}

// ---------------- K3b: WM[b,o,c] = M[b,o,:] @ WqT[c,:]  (MFMA, double-buffered) ----------------
__global__ __launch_bounds__(512) void k3b_mfma(
    const short* __restrict__ M, const short* __restrict__ wqT,
    short* __restrict__ WM)
{
  const int ct = blockIdx.x, b = blockIdx.y;
  const int tid = threadIdx.x, w = tid >> 6, l = tid & 63;
  const int l15 = l & 15, l4 = l >> 4;

  __shared__ __align__(16) char sm3[81920];   // 2 x (At 32K + Bt 8K)

  f32x4 acc[4][2];
#pragma unroll
  for (int i = 0; i < 4; ++i)
#pragma unroll
    for (int jj = 0; jj < 2; ++jj) acc[i][jj] = (f32x4){0.f, 0.f, 0.f, 0.f};

  const int srow = tid >> 3, scol = (tid & 7) * 16;
  auto issue = [&](int st, int pb) {
    char* Ab = sm3 + pb * 40960;
    char* Bb = sm3 + 32768 + pb * 40960;
#pragma unroll
    for (int p = 0; p < 4; ++p) {
      int row = p * 64 + srow;
      const char* src = (const char*)M + ((size_t)b * OC + row) * 1024 + st * 128
                        + (scol ^ ((row & 7) << 4));
      gl16(src, Ab + (size_t)(p * 64 + w * 8) * 128);
    }
    {
      int row = srow;
      const char* src = (const char*)wqT + (size_t)(ct * 64 + row) * 1024 + st * 128
                        + (scol ^ ((row & 7) << 4));
      gl16(src, Bb + (size_t)(w * 8) * 128);
    }
  };

  issue(0, 0);
  for (int st = 0; st < 8; ++st) {
    const int pb = st & 1;
    if (st < 7) { issue(st + 1, pb ^ 1); VMCNT(5); } else { VMCNT(0); }
    barrier_fence();
    char* At = sm3 + pb * 40960;
    char* Bt = sm3 + 32768 + pb * 40960;
#pragma unroll
    for (int kk = 0; kk < 2; ++kk) {
      bf16x8 afr[4], bfr[2];
#pragma unroll
      for (int tr = 0; tr < 4; ++tr) {
        int o = (w >> 1) * 64 + tr * 16 + l15;
        afr[tr] = *(bf16x8*)(At + (size_t)o * 128 + ((kk * 64 + l4 * 16) ^ ((o & 7) << 4)));
      }
#pragma unroll
      for (int tn = 0; tn < 2; ++tn) {
        int c = (w & 1) * 32 + tn * 16 + l15;
        bfr[tn] = *(bf16x8*)(Bt + (size_t)c * 128 + ((kk * 64 + l4 * 16) ^ ((c & 7) << 4)));
      }
#pragma unroll
      for (int tr = 0; tr < 4; ++tr)
#pragma unroll
        for (int tn = 0; tn < 2; ++tn)
          acc[tr][tn] = __builtin_amdgcn_mfma_f32_16x16x32_bf16(afr[tr], bfr[tn], acc[tr][tn], 0, 0, 0);
    }
    barrier_fence();
  }
#pragma unroll
  for (int tr = 0; tr < 4; ++tr) {
#pragma unroll
    for (int tn = 0; tn < 2; ++tn) {
#pragma unroll
      for (int rg = 0; rg < 4; ++rg) {
        int o = (w >> 1) * 64 + tr * 16 + l4 * 4 + rg;
        int c = ct * 64 + (w & 1) * 32 + tn * 16 + l15;
        WM[((size_t)b * OC + o) * CIN + c] = f2bf(acc[tr][tn][rg]);
      }
    }
  }
}

// ---------------- K4: out = WM @ imgT^T + b_out (WM-in-regs, pipelined) ----------------
__global__ __launch_bounds__(512, 2) void k4_mfma(
    const short* __restrict__ WM, const short* __restrict__ imgT,
    const float* __restrict__ b_out, float* __restrict__ out)
{
  const int bi = blockIdx.x;
  const int b = bi & 7, nt = bi >> 3;
  const int n0 = nt * 64;
  const int tid = threadIdx.x, w = tid >> 6, l = tid & 63;
  const int l15 = l & 15, l4 = l >> 4;

  __shared__ __align__(16) char sm4[24576];
  char* B0 = sm4; char* B1 = sm4 + 8192; char* B2 = sm4 + 16384;

  bf16x8 wreg[2][4][2];
#pragma unroll
  for (int tr = 0; tr < 2; ++tr) {
    int o = w * 32 + tr * 16 + l15;
    const char* base = (const char*)WM + ((size_t)b * OC + o) * 512;
#pragma unroll
    for (int kq = 0; kq < 4; ++kq)
#pragma unroll
      for (int kk = 0; kk < 2; ++kk)
        wreg[tr][kq][kk] = *(const bf16x8*)(base + kq * 128 + kk * 64 + l4 * 16);
  }
  VMCNT(0);

  const char* ibase = (const char*)imgT + ((size_t)b * NSP + n0) * 512;
  const int rowpart = w * 8 + (l >> 3);
  const int colswz = ((l & 7) * 16) ^ (((l >> 3) & 7) << 4);

  auto issue_x = [&](char* buf, int q) {
    const char* src = ibase + (size_t)rowpart * 512 + q * 128 + colswz;
    gl16(src, buf + (size_t)(w * 8) * 128);
  };

  f32x4 acc[2][4];
#pragma unroll
  for (int i = 0; i < 2; ++i)
#pragma unroll
    for (int jj = 0; jj < 4; ++jj) acc[i][jj] = (f32x4){0.f, 0.f, 0.f, 0.f};

#define K4Q(BUF, Q)                                                       \
  {                                                                       \
    _Pragma("unroll")                                                     \
    for (int kk = 0; kk < 2; ++kk) {                                      \
      bf16x8 bfr[4];                                                      \
      _Pragma("unroll")                                                   \
      for (int tn = 0; tn < 4; ++tn) {                                    \
        int n = tn * 16 + l15;                                            \
        bfr[tn] = *(bf16x8*)((BUF) + (size_t)n * 128 +                    \
                  ((kk * 64 + l4 * 16) ^ ((n & 7) << 4)));                \
      }                                                                   \
      __builtin_amdgcn_s_setprio(1);                                      \
      _Pragma("unroll")                                                   \
      for (int tr = 0; tr < 2; ++tr)                                      \
        _Pragma("unroll")                                                 \
        for (int tn = 0; tn < 4; ++tn)                                    \
          acc[tr][tn] = __builtin_amdgcn_mfma_f32_16x16x32_bf16(          \
              wreg[tr][Q][kk], bfr[tn], acc[tr][tn], 0, 0, 0);            \
      __builtin_amdgcn_s_setprio(0);                                      \
    }                                                                     \
  }

  issue_x(B0, 0);
  issue_x(B1, 1);

  VMCNT(1); barrier_fence();
  issue_x(B2, 2);
  K4Q(B0, 0);

  VMCNT(1); barrier_fence();
  issue_x(B0, 3);
  K4Q(B1, 1);

  VMCNT(1); barrier_fence();
  K4Q(B2, 2);

  VMCNT(0); barrier_fence();
  K4Q(B0, 3);

#pragma unroll
  for (int tr = 0; tr < 2; ++tr) {
#pragma unroll
    for (int rg = 0; rg < 4; ++rg) {
      int o = w * 32 + tr * 16 + l4 * 4 + rg;
      float bo = b_out[o];
#pragma unroll
      for (int tn = 0; tn < 4; ++tn) {
        int n = n0 + tn * 16 + l15;
        out[((size_t)b * OC + o) * NSP + n] = acc[tr][tn][rg] + bo;
      }
    }
  }
}

extern "C" void kernel_launch(void* const* d_in, const int* in_sizes, int n_in,
                              void* d_out, int out_size, void* d_ws, size_t ws_size,
                              hipStream_t stream) {
  (void)in_sizes; (void)n_in; (void)out_size; (void)ws_size;
  const float* img   = (const float*)d_in[0];
  const float* w_qkv = (const float*)d_in[1];
  const float* w_out = (const float*)d_in[2];
  const float* b_out = (const float*)d_in[3];
  float* out = (float*)d_out;

  char* ws = (char*)d_ws;
  short* imgT     = (short*)ws;                   // 16,777,216
  short* wkv      = (short*)(ws + 16777216);      //    524,288
  short* wqT      = (short*)(ws + 17301504);      //    262,144
  float* ctx_part = (float*)(ws + 17563648);      //  8,388,608 (64 bh x 8 ch x 4096)
  float* z_part   = (float*)(ws + 25952256);      //    131,072
  short* Mbuf     = (short*)(ws + 26083328);      //  2,097,152
  short* WMbuf    = (short*)(ws + 28180480);      //  1,048,576 (end ~29.2 MB)

  prep<<<dim3(2336), 256, 0, stream>>>(img, w_qkv, imgT, wkv, wqT);
  k1_mfma<<<dim3(512), 256, 0, stream>>>(imgT, wkv, ctx_part, z_part);
  k23_fold<<<dim3(256), 256, 0, stream>>>(ctx_part, z_part, w_out, Mbuf);
  k3b_mfma<<<dim3(4, 8), 512, 0, stream>>>(Mbuf, wqT, WMbuf);
  k4_mfma<<<dim3(512), 512, 0, stream>>>(WMbuf, imgT, b_out, out);
}